// Round 14
// baseline (188.040 us; speedup 1.0000x reference)
//
#include <hip/hip_runtime.h>
#include <hip/hip_bf16.h>

// Dims (compile-time constants from the reference)
#define D_MODEL 1024
#define D_STATE 16
#define D_CONV  4
#define D_INNER 2048
#define DT_RANK 64
#define BATCH   2
#define SEQLEN  1024
#define NROWS   (BATCH * SEQLEN)        // 2048
#define XDBL_W  (DT_RANK + 2 * D_STATE) // 96
#define NCHUNK  64                      // chunks per sequence
#define LCHUNK  16                      // steps per chunk
#define NCHAN   (BATCH * D_INNER)       // 4096 (b,e) channels
#define KSPLIT_XDBL 8

typedef unsigned short ushort_t;
typedef __attribute__((ext_vector_type(8))) short bf16x8;
typedef __attribute__((ext_vector_type(8))) unsigned short ushort8v;
typedef __attribute__((ext_vector_type(4))) float f32x4;

// fp32 -> bf16 (round-to-nearest-even), bit-level (deterministic)
__device__ __forceinline__ ushort_t f2bf(float f) {
    union { float f; unsigned u; } v; v.f = f;
    unsigned r = v.u + 0x7fffu + ((v.u >> 16) & 1u);
    return (ushort_t)(r >> 16);
}
__device__ __forceinline__ float bf2f(ushort_t h) {
    union { unsigned u; float f; } v; v.u = (unsigned)h << 16; return v.f;
}
__device__ __forceinline__ float fast_sigmoid(float z) {
    return __builtin_amdgcn_rcpf(1.f + __expf(-z));
}

// ---------------------------------------------------------------------------
// Mega-prologue: LayerNorm (2048 blocks) + 4 weight transpose-converts.
// ---------------------------------------------------------------------------
#define PRO_LN1   2048
#define PRO_TIN1  6144
#define PRO_TOUT1 8192
#define PRO_TXP1  8448
#define PRO_TOTAL 8576

__device__ __forceinline__ void transpose_job(const float* __restrict__ W,
                                              ushort_t* __restrict__ Wt,
                                              int R, int Creal,
                                              int cx, int ry, int tid,
                                              float t[32][33])
{
    int c0 = cx * 32, r0 = ry * 32;
    int tx = tid & 31, ty = tid >> 5;
    int col = c0 + tx;
    #pragma unroll
    for (int i = 0; i < 32; i += 8) {
        float v = (col < Creal) ? W[(size_t)(r0 + ty + i) * Creal + col] : 0.f;
        t[ty + i][tx] = v;
    }
    __syncthreads();
    #pragma unroll
    for (int i = 0; i < 32; i += 8)
        Wt[(size_t)(c0 + ty + i) * R + r0 + tx] = f2bf(t[tx][ty + i]);
}

__global__ __launch_bounds__(256)
void prologue_kernel(const float* __restrict__ x, const float* __restrict__ g,
                     const float* __restrict__ bb, ushort_t* __restrict__ xnbf,
                     const float* __restrict__ W_in, ushort_t* __restrict__ WtIn,
                     const float* __restrict__ W_out, ushort_t* __restrict__ WtOut,
                     const float* __restrict__ W_xp, ushort_t* __restrict__ WtXp,
                     const float* __restrict__ W_dt, ushort_t* __restrict__ WtDt)
{
    __shared__ float t[32][33];
    __shared__ float red[8];
    int bid = blockIdx.x;
    int tid = threadIdx.x;

    if (bid < PRO_LN1) {
        const float* xr = x + (size_t)bid * D_MODEL;
        float4 v = reinterpret_cast<const float4*>(xr)[tid];
        float s  = v.x + v.y + v.z + v.w;
        float ss = v.x * v.x + v.y * v.y + v.z * v.z + v.w * v.w;
        #pragma unroll
        for (int off = 32; off; off >>= 1) {
            s  += __shfl_down(s, off);
            ss += __shfl_down(ss, off);
        }
        int wid = tid >> 6, lane = tid & 63;
        if (lane == 0) { red[wid] = s; red[4 + wid] = ss; }
        __syncthreads();
        if (tid == 0) {
            float st = 0.f, sst = 0.f;
            #pragma unroll
            for (int i = 0; i < 4; ++i) { st += red[i]; sst += red[4 + i]; }
            red[0] = st; red[4] = sst;
        }
        __syncthreads();
        float mu  = red[0] * (1.f / D_MODEL);
        float var = red[4] * (1.f / D_MODEL) - mu * mu;
        float inv = rsqrtf(var + 1e-5f);
        float4 gv = reinterpret_cast<const float4*>(g)[tid];
        float4 bv = reinterpret_cast<const float4*>(bb)[tid];
        ushort4 o;
        o.x = f2bf((v.x - mu) * inv * gv.x + bv.x);
        o.y = f2bf((v.y - mu) * inv * gv.y + bv.y);
        o.z = f2bf((v.z - mu) * inv * gv.z + bv.z);
        o.w = f2bf((v.w - mu) * inv * gv.w + bv.w);
        reinterpret_cast<ushort4*>(xnbf + (size_t)bid * D_MODEL)[tid] = o;
    } else if (bid < PRO_TIN1) {
        int j = bid - PRO_LN1;
        transpose_job(W_in, WtIn, D_MODEL, 2 * D_INNER, j & 127, j >> 7, tid, t);
    } else if (bid < PRO_TOUT1) {
        int j = bid - PRO_TIN1;
        transpose_job(W_out, WtOut, D_INNER, D_MODEL, j & 31, j >> 5, tid, t);
    } else if (bid < PRO_TXP1) {
        int j = bid - PRO_TOUT1;
        transpose_job(W_xp, WtXp, D_INNER, XDBL_W, j & 3, j >> 2, tid, t);
    } else {
        int j = bid - PRO_TXP1;
        transpose_job(W_dt, WtDt, DT_RANK, D_INNER, j & 63, j >> 6, tid, t);
    }
}

// ---- T2 both-sides swizzle (rule #21): LDS dest stays lane-linear;
// the GLOBAL source chunk is pre-permuted gc=(chunk)^(row&7), reads XOR the
// slot identically. Each 8-lane group still loads one contiguous 128B row.

// 64 rows x 64 k bf16 (8KB), [64][64], swizzled.
__device__ __forceinline__ void stage64x64_swz(const ushort_t* __restrict__ gbase,
                                               size_t ld, ushort_t* ldsb, int tid)
{
    int l = tid & 63;
    int w = tid >> 6;
    int gc = (l & 7) ^ (l >> 3);               // row&7 == l>>3 here
    #pragma unroll
    for (int i = 0; i < 2; ++i) {
        int row = i * 32 + w * 8 + (l >> 3);
        const ushort_t* src = gbase + (size_t)row * ld + gc * 8;
        char* dst = (char*)ldsb + (i * 32 + w * 8) * 128;
        __builtin_amdgcn_global_load_lds(
            (const __attribute__((address_space(1))) unsigned*)src,
            (__attribute__((address_space(3))) unsigned*)dst, 16, 0, 0);
    }
}

// 128 rows x 64 k bf16 (16KB), [128][64], swizzled.
__device__ __forceinline__ void stage128x64_swz(const ushort_t* __restrict__ gbase,
                                                size_t ld, ushort_t* ldsb, int tid)
{
    int l = tid & 63;
    int w = tid >> 6;
    int gc = (l & 7) ^ (l >> 3);
    #pragma unroll
    for (int i = 0; i < 4; ++i) {
        int row = i * 32 + w * 8 + (l >> 3);
        const ushort_t* src = gbase + (size_t)row * ld + gc * 8;
        char* dst = (char*)ldsb + (i * 32 + w * 8) * 128;
        __builtin_amdgcn_global_load_lds(
            (const __attribute__((address_space(1))) unsigned*)src,
            (__attribute__((address_space(3))) unsigned*)dst, 16, 0, 0);
    }
}

// 16 rows x 64 k bf16 (2KB), [16][64], swizzled; waves 0-1 only.
__device__ __forceinline__ void stage16x64_swz(const ushort_t* __restrict__ gbase,
                                               size_t ld, ushort_t* ldsb, int tid)
{
    int l = tid & 63;
    int w = tid >> 6;
    if (w < 2) {
        int row = w * 8 + (l >> 3);
        int gc = (l & 7) ^ (l >> 3);
        const ushort_t* src = gbase + (size_t)row * ld + gc * 8;
        char* dst = (char*)ldsb + w * 8 * 128;
        __builtin_amdgcn_global_load_lds(
            (const __attribute__((address_space(1))) unsigned*)src,
            (__attribute__((address_space(3))) unsigned*)dst, 16, 0, 0);
    }
}

// ---------------------------------------------------------------------------
// Fused xz GEMM + causal conv + SiLU (swizzled LDS, rolling-window conv).
// ---------------------------------------------------------------------------
__global__ __launch_bounds__(256)
void gemm_xz_conv(const ushort_t* __restrict__ A, const ushort_t* __restrict__ Bt,
                  ushort_t* __restrict__ xzbf,
                  const float* __restrict__ cw, const float* __restrict__ cb,
                  ushort_t* __restrict__ u2bf)
{
    // union: loop {As 8192, Bs 8192, As2 1024 ushorts}; epilogue T[144][130]
    __shared__ ushort_t smem[18720];
    ushort_t* As  = smem;
    ushort_t* Bs  = smem + 8192;
    ushort_t* As2 = smem + 16384;
    const int K = D_MODEL, N = 2 * D_INNER;
    int bid = blockIdx.x;                       // 512
    int swzb = ((bid & 7) << 6) + (bid >> 3);   // XCD-aware swizzle
    int bx = swzb & 31, by = swzb >> 5;
    bool isU = (bx < 16);
    int tid = threadIdx.x;
    int l = tid & 63, wid = tid >> 6;
    int wr = wid >> 1, wc = wid & 1;
    int row0 = by * 128, col0 = bx * 128;
    int l0 = row0 & (SEQLEN - 1);

    f32x4 acc[4][4];
    #pragma unroll
    for (int m = 0; m < 4; ++m)
        #pragma unroll
        for (int n = 0; n < 4; ++n)
            acc[m][n] = (f32x4){0.f, 0.f, 0.f, 0.f};
    f32x4 acc2[4];
    #pragma unroll
    for (int n = 0; n < 4; ++n) acc2[n] = (f32x4){0.f, 0.f, 0.f, 0.f};

    if (isU && l0 == 0)
        reinterpret_cast<ushort4*>(As2)[tid] = (ushort4){0, 0, 0, 0};

    const ushort_t* Ab  = A  + (size_t)row0 * K;
    const ushort_t* Ab2 = A  + (size_t)(row0 - 16) * K;   // valid iff l0 != 0
    const ushort_t* Bb  = Bt + (size_t)col0 * K;
    int arow = wr * 64 + (l & 15);
    int brow = wc * 64 + (l & 15);

    for (int k0 = 0; k0 < K; k0 += 64) {
        stage128x64_swz(Ab + k0, K, As, tid);
        stage128x64_swz(Bb + k0, K, Bs, tid);
        if (isU && l0 != 0) stage16x64_swz(Ab2 + k0, K, As2, tid);
        __syncthreads();
        #pragma unroll
        for (int ks = 0; ks < 2; ++ks) {
            int sw = (((ks * 4 + (l >> 4)) ^ (l & 7)) * 8);
            bf16x8 af[4], bfr[4];
            #pragma unroll
            for (int m = 0; m < 4; ++m)
                af[m] = *reinterpret_cast<const bf16x8*>(
                    &As[(arow + m * 16) * 64 + sw]);
            #pragma unroll
            for (int n = 0; n < 4; ++n)
                bfr[n] = *reinterpret_cast<const bf16x8*>(
                    &Bs[(brow + n * 16) * 64 + sw]);
            #pragma unroll
            for (int m = 0; m < 4; ++m)
                #pragma unroll
                for (int n = 0; n < 4; ++n)
                    acc[m][n] = __builtin_amdgcn_mfma_f32_16x16x32_bf16(
                        af[m], bfr[n], acc[m][n], 0, 0, 0);
            if (isU && wr == 0) {
                bf16x8 af2 = *reinterpret_cast<const bf16x8*>(
                    &As2[(l & 15) * 64 + sw]);
                #pragma unroll
                for (int n = 0; n < 4; ++n)
                    acc2[n] = __builtin_amdgcn_mfma_f32_16x16x32_bf16(
                        af2, bfr[n], acc2[n], 0, 0, 0);
            }
        }
        __syncthreads();
    }

    int ro = (l >> 4) * 4, co = l & 15;
    if (isU) {
        // ---- stage bf16 tile (+boundary rows) into T[144][130] ----
        #pragma unroll
        for (int m = 0; m < 4; ++m)
            #pragma unroll
            for (int n = 0; n < 4; ++n) {
                int c = wc * 64 + n * 16 + co;
                #pragma unroll
                for (int reg = 0; reg < 4; ++reg) {
                    int r = 16 + wr * 64 + m * 16 + ro + reg;
                    smem[r * 130 + c] = f2bf(acc[m][n][reg]);
                }
            }
        if (wr == 0) {
            #pragma unroll
            for (int n = 0; n < 4; ++n) {
                int c = wc * 64 + n * 16 + co;
                #pragma unroll
                for (int reg = 0; reg < 4; ++reg)
                    smem[(ro + reg) * 130 + c] = f2bf(acc2[n][reg]);
            }
        }
        __syncthreads();
        // ---- conv(4-tap causal) + bias + SiLU, rolling window -> u2bf ----
        int c = tid & 127;
        int half = tid >> 7;                   // 0 or 1
        int r0 = half * 64;
        int e = col0 + c;
        float4 w4 = *reinterpret_cast<const float4*>(cw + (size_t)e * 4);
        float cbv = cb[e];
        float h0 = bf2f(smem[(r0 + 13) * 130 + c]);
        float h1 = bf2f(smem[(r0 + 14) * 130 + c]);
        float h2 = bf2f(smem[(r0 + 15) * 130 + c]);
        #pragma unroll
        for (int j = 0; j < 64; ++j) {
            float cur = bf2f(smem[(r0 + 16 + j) * 130 + c]);
            float a = cbv + h0 * w4.x + h1 * w4.y + h2 * w4.z + cur * w4.w;
            u2bf[(size_t)(row0 + r0 + j) * D_INNER + e] = f2bf(a * fast_sigmoid(a));
            h0 = h1; h1 = h2; h2 = cur;
        }
    } else {
        // z-tile: standard bf16 store (gate input for scan_final)
        #pragma unroll
        for (int m = 0; m < 4; ++m) {
            #pragma unroll
            for (int n = 0; n < 4; ++n) {
                int c = col0 + wc * 64 + n * 16 + co;
                #pragma unroll
                for (int reg = 0; reg < 4; ++reg) {
                    int r = row0 + wr * 64 + m * 16 + ro + reg;
                    xzbf[(size_t)r * N + c] = f2bf(acc[m][n][reg]);
                }
            }
        }
    }
}

// ---------------------------------------------------------------------------
// Fused dt GEMM, single BK=64 iteration (K=DT_RANK=64), swizzled LDS.
// A[128][64] = sum of 8 split-K fp32 planes, written with write-side swizzle;
// B[128][64] via swizzled async stage. Epilogue: softplus(acc + b_dt) -> bf16.
// bx==0 blocks additionally emit xdblBC[2048][32] bf16 (B/C cols 64..96).
// ---------------------------------------------------------------------------
__global__ __launch_bounds__(256)
void gemm_dt_fused(const float* __restrict__ parts, const ushort_t* __restrict__ Bt,
                   ushort_t* __restrict__ dtb, const float* __restrict__ bias,
                   ushort_t* __restrict__ xdblBC)
{
    __shared__ ushort_t As[128 * 64];
    __shared__ ushort_t Bs[128 * 64];
    const int K = DT_RANK;   // 64
    int tid = threadIdx.x;
    int l = tid & 63, wid = tid >> 6;
    int wr = wid >> 1, wc = wid & 1;
    int row0 = blockIdx.y * 128, col0 = blockIdx.x * 128;

    // Side job (16 blocks): reduce B/C columns 64..96 to bf16 xdblBC.
    if (blockIdx.x == 0) {
        #pragma unroll
        for (int i = 0; i < 16; ++i) {
            int e2 = tid + 256 * i;             // 0..4095
            int rr = e2 >> 5, cc = e2 & 31;
            size_t r = (size_t)(row0 + rr);
            float s = 0.f;
            #pragma unroll
            for (int z = 0; z < KSPLIT_XDBL; ++z)
                s += parts[(size_t)z * NROWS * XDBL_W + r * XDBL_W + 64 + cc];
            xdblBC[r * 32 + cc] = f2bf(s);
        }
    }

    // B stage (async, swizzled)
    stage128x64_swz(Bt + (size_t)col0 * K, K, Bs, tid);

    // A stage: [128][64] reduced from 8 fp32 planes, WRITE-side swizzle
    // (same involution as the read: slot ^= row&7).
    #pragma unroll
    for (int i = 0; i < 32; ++i) {
        int e2 = tid + 256 * i;                 // 0..8191
        int rr = e2 >> 6, cc = e2 & 63;
        size_t r = (size_t)(row0 + rr);
        float s = 0.f;
        #pragma unroll
        for (int z = 0; z < KSPLIT_XDBL; ++z)
            s += parts[(size_t)z * NROWS * XDBL_W + r * XDBL_W + cc];
        int slot = (cc >> 3) ^ (rr & 7);
        As[rr * 64 + slot * 8 + (cc & 7)] = f2bf(s);
    }
    __syncthreads();

    f32x4 acc[4][4];
    #pragma unroll
    for (int m = 0; m < 4; ++m)
        #pragma unroll
        for (int n = 0; n < 4; ++n)
            acc[m][n] = (f32x4){0.f, 0.f, 0.f, 0.f};

    int arow = wr * 64 + (l & 15);
    int brow = wc * 64 + (l & 15);
    #pragma unroll
    for (int ks = 0; ks < 2; ++ks) {
        int sw = (((ks * 4 + (l >> 4)) ^ (l & 7)) * 8);
        bf16x8 af[4], bfr[4];
        #pragma unroll
        for (int m = 0; m < 4; ++m)
            af[m] = *reinterpret_cast<const bf16x8*>(&As[(arow + m * 16) * 64 + sw]);
        #pragma unroll
        for (int n = 0; n < 4; ++n)
            bfr[n] = *reinterpret_cast<const bf16x8*>(&Bs[(brow + n * 16) * 64 + sw]);
        #pragma unroll
        for (int m = 0; m < 4; ++m)
            #pragma unroll
            for (int n = 0; n < 4; ++n)
                acc[m][n] = __builtin_amdgcn_mfma_f32_16x16x32_bf16(
                    af[m], bfr[n], acc[m][n], 0, 0, 0);
    }

    int ro = (l >> 4) * 4, co = l & 15;
    #pragma unroll
    for (int m = 0; m < 4; ++m) {
        #pragma unroll
        for (int n = 0; n < 4; ++n) {
            int c = col0 + wc * 64 + n * 16 + co;
            float bdt = bias[c];
            #pragma unroll
            for (int reg = 0; reg < 4; ++reg) {
                int r = row0 + wr * 64 + m * 16 + ro + reg;
                float v = acc[m][n][reg] + bdt;
                v = (v > 20.f) ? v : __logf(1.f + __expf(v));   // softplus
                dtb[(size_t)r * D_INNER + c] = f2bf(v);
            }
        }
    }
}

// ---------------------------------------------------------------------------
// xdbl split-K GEMM, 64x128 tile, BK=64 swizzled:
// parts[z][64-row-block][96] = u2 x WtXp^T over K-range.
// ---------------------------------------------------------------------------
__global__ __launch_bounds__(256)
void gemm_xdbl64(const ushort_t* __restrict__ A, const ushort_t* __restrict__ Bt,
                 float* __restrict__ parts)
{
    __shared__ ushort_t As[64 * 64];
    __shared__ ushort_t Bs[128 * 64];
    const int K = D_INNER;
    const int KS = D_INNER / KSPLIT_XDBL;      // 256
    int tid = threadIdx.x;
    int l = tid & 63, wid = tid >> 6;
    int wr = wid >> 1, wc = wid & 1;
    int row0 = blockIdx.y * 64;
    int kbeg = blockIdx.z * KS;

    f32x4 acc[2][4];
    #pragma unroll
    for (int m = 0; m < 2; ++m)
        #pragma unroll
        for (int n = 0; n < 4; ++n)
            acc[m][n] = (f32x4){0.f, 0.f, 0.f, 0.f};

    const ushort_t* Ab = A  + (size_t)row0 * K + kbeg;
    const ushort_t* Bb = Bt + kbeg;
    int arow = wr * 32 + (l & 15);
    int brow = wc * 64 + (l & 15);

    #pragma unroll
    for (int k0 = 0; k0 < KS; k0 += 64) {
        stage64x64_swz(Ab + k0, K, As, tid);
        stage128x64_swz(Bb + k0, K, Bs, tid);
        __syncthreads();
        #pragma unroll
        for (int ks = 0; ks < 2; ++ks) {
            int sw = (((ks * 4 + (l >> 4)) ^ (l & 7)) * 8);
            bf16x8 af[2], bfr[4];
            #pragma unroll
            for (int m = 0; m < 2; ++m)
                af[m] = *reinterpret_cast<const bf16x8*>(
                    &As[(arow + m * 16) * 64 + sw]);
            #pragma unroll
            for (int n = 0; n < 4; ++n)
                bfr[n] = *reinterpret_cast<const bf16x8*>(
                    &Bs[(brow + n * 16) * 64 + sw]);
            #pragma unroll
            for (int m = 0; m < 2; ++m)
                #pragma unroll
                for (int n = 0; n < 4; ++n)
                    acc[m][n] = __builtin_amdgcn_mfma_f32_16x16x32_bf16(
                        af[m], bfr[n], acc[m][n], 0, 0, 0);
        }
        __syncthreads();
    }

    float* Cp = parts + (size_t)blockIdx.z * NROWS * XDBL_W;
    int ro = (l >> 4) * 4, co = l & 15;
    #pragma unroll
    for (int m = 0; m < 2; ++m) {
        #pragma unroll
        for (int n = 0; n < 4; ++n) {
            int c = wc * 64 + n * 16 + co;
            if (c >= XDBL_W) continue;
            #pragma unroll
            for (int reg = 0; reg < 4; ++reg) {
                int r = row0 + wr * 32 + m * 16 + ro + reg;
                Cp[(size_t)r * XDBL_W + c] = acc[m][n][reg];
            }
        }
    }
}

// ---------------------------------------------------------------------------
// out GEMM, 64x64 tile, BK=64, swizzled LDS: out = x + rs * (ybf x WtOut^T).
// ---------------------------------------------------------------------------
__global__ __launch_bounds__(256)
void gemm_out64(const ushort_t* __restrict__ A, const ushort_t* __restrict__ Bt,
                const float* __restrict__ x, const float* __restrict__ res_scale,
                float* __restrict__ out)
{
    __shared__ ushort_t As[64 * 64];
    __shared__ ushort_t Bs[64 * 64];
    const int K = D_INNER, N = D_MODEL;
    int bid = blockIdx.x;                       // 512
    int swzb = ((bid & 7) << 6) + (bid >> 3);
    int bx = swzb & 15, by = swzb >> 4;
    int tid = threadIdx.x;
    int l = tid & 63, wid = tid >> 6;
    int wr = wid >> 1, wc = wid & 1;
    int row0 = by * 64, col0 = bx * 64;

    f32x4 acc[2][2];
    #pragma unroll
    for (int m = 0; m < 2; ++m)
        #pragma unroll
        for (int n = 0; n < 2; ++n)
            acc[m][n] = (f32x4){0.f, 0.f, 0.f, 0.f};

    const ushort_t* Ab = A  + (size_t)row0 * K;
    const ushort_t* Bb = Bt + (size_t)col0 * K;
    int arow = wr * 32 + (l & 15);
    int brow = wc * 32 + (l & 15);

    for (int k0 = 0; k0 < K; k0 += 64) {
        stage64x64_swz(Ab + k0, K, As, tid);
        stage64x64_swz(Bb + k0, K, Bs, tid);
        __syncthreads();
        #pragma unroll
        for (int ks = 0; ks < 2; ++ks) {
            int sw = (((ks * 4 + (l >> 4)) ^ (l & 7)) * 8);
            bf16x8 af[2], bfr[2];
            #pragma unroll
            for (int m = 0; m < 2; ++m)
                af[m] = *reinterpret_cast<const bf16x8*>(
                    &As[(arow + m * 16) * 64 + sw]);
            #pragma unroll
            for (int n = 0; n < 2; ++n)
                bfr[n] = *reinterpret_cast<const bf16x8*>(
                    &Bs[(brow + n * 16) * 64 + sw]);
            #pragma unroll
            for (int m = 0; m < 2; ++m)
                #pragma unroll
                for (int n = 0; n < 2; ++n)
                    acc[m][n] = __builtin_amdgcn_mfma_f32_16x16x32_bf16(
                        af[m], bfr[n], acc[m][n], 0, 0, 0);
        }
        __syncthreads();
    }

    float rs = res_scale[0];
    int ro = (l >> 4) * 4, co = l & 15;
    #pragma unroll
    for (int m = 0; m < 2; ++m) {
        #pragma unroll
        for (int n = 0; n < 2; ++n) {
            int c = col0 + wc * 32 + n * 16 + co;
            #pragma unroll
            for (int reg = 0; reg < 4; ++reg) {
                int r = row0 + wr * 32 + m * 16 + ro + reg;
                out[(size_t)r * N + c] = x[(size_t)r * N + c] + rs * acc[m][n][reg];
            }
        }
    }
}

// ---------------------------------------------------------------------------
// Chunked scan, pass A: one thread per (channel, chunk); 16 states in regs.
// ---------------------------------------------------------------------------
__global__ __launch_bounds__(256)
void scan_partial_kernel(const ushort_t* __restrict__ dtb,
                         const ushort_t* __restrict__ xdblBC,
                         const ushort_t* __restrict__ u2bf,
                         const float* __restrict__ A_log,
                         ushort_t* __restrict__ hend, float* __restrict__ sumdt_buf)
{
    int idx = blockIdx.x * 256 + threadIdx.x;   // 0 .. NCHAN*NCHUNK-1
    int p = idx & (NCHAN - 1);                  // channel (64 consecutive/wave)
    int c = idx >> 12;                          // chunk
    int b = p >> 11, e = p & (D_INNER - 1);

    float An[D_STATE];
    {
        const float4* ar = reinterpret_cast<const float4*>(A_log + (size_t)e * D_STATE);
        #pragma unroll
        for (int q = 0; q < 4; ++q) {
            float4 a4 = ar[q];
            An[q * 4 + 0] = -__expf(a4.x);
            An[q * 4 + 1] = -__expf(a4.y);
            An[q * 4 + 2] = -__expf(a4.z);
            An[q * 4 + 3] = -__expf(a4.w);
        }
    }
    float h[D_STATE];
    #pragma unroll
    for (int n = 0; n < D_STATE; ++n) h[n] = 0.f;
    float sdt = 0.f;

    size_t rowbase = (size_t)b * SEQLEN + c * LCHUNK;
    #pragma unroll
    for (int j = 0; j < LCHUNK; ++j) {
        size_t row = rowbase + j;
        float dt = bf2f(dtb[row * D_INNER + e]);
        float u  = bf2f(u2bf[row * D_INNER + e]);
        float dtu = dt * u;
        sdt += dt;
        const ushort8v* xr = reinterpret_cast<const ushort8v*>(xdblBC + row * 32);
        ushort8v b0 = xr[0], b1 = xr[1];
        float Bv[D_STATE];
        #pragma unroll
        for (int q = 0; q < 8; ++q) { Bv[q] = bf2f(b0[q]); Bv[8 + q] = bf2f(b1[q]); }
        #pragma unroll
        for (int n = 0; n < D_STATE; ++n)
            h[n] = __expf(dt * An[n]) * h[n] + dtu * Bv[n];
    }

    ushort8v o0, o1;
    #pragma unroll
    for (int q = 0; q < 8; ++q) { o0[q] = f2bf(h[q]); o1[q] = f2bf(h[8 + q]); }
    ushort8v* hp = reinterpret_cast<ushort8v*>(hend + ((size_t)p * NCHUNK + c) * D_STATE);
    hp[0] = o0; hp[1] = o1;
    sumdt_buf[p * NCHUNK + c] = sdt;
}

// ---------------------------------------------------------------------------
// Pass B: per-channel inter-chunk Hillis-Steele scan (fp32 in LDS);
// reads bf16 hend, writes bf16 exclusive carry in place.
// ---------------------------------------------------------------------------
__global__ __launch_bounds__(1024)
void scan_combine_kernel(const float* __restrict__ A_log,
                         const float* __restrict__ sumdt_buf,
                         ushort_t* __restrict__ hend /* in: hend, out: hcarry */)
{
    __shared__ float Ps[NCHUNK][D_STATE];
    __shared__ float Hs[NCHUNK][D_STATE];
    int tid = threadIdx.x;
    int c = tid >> 4, n = tid & 15;
    int p = blockIdx.x;
    int e = p & (D_INNER - 1);
    float An = -__expf(A_log[e * D_STATE + n]);
    float P = __expf(An * sumdt_buf[p * NCHUNK + c]);
    float H = bf2f(hend[(size_t)p * (NCHUNK * D_STATE) + c * D_STATE + n]);
    Ps[c][n] = P; Hs[c][n] = H;
    __syncthreads();
    #pragma unroll
    for (int d = 1; d < NCHUNK; d <<= 1) {
        float Pl = 1.f, Hl = 0.f;
        if (c >= d) { Pl = Ps[c - d][n]; Hl = Hs[c - d][n]; }
        __syncthreads();
        H = P * Hl + H;   // (P,H) o (Pl,Hl)
        P = P * Pl;
        Ps[c][n] = P; Hs[c][n] = H;
        __syncthreads();
    }
    float carry = (c == 0) ? 0.f : Hs[c - 1][n];
    hend[(size_t)p * (NCHUNK * D_STATE) + c * D_STATE + n] = f2bf(carry);
}

// ---------------------------------------------------------------------------
// Pass C: one thread per (channel, chunk), seeded with bf16 carry; in-register
// dot with C row; fused D-skip + SiLU(z) gate; writes y as bf16.
// ---------------------------------------------------------------------------
__global__ __launch_bounds__(256)
void scan_final_kernel(const ushort_t* __restrict__ dtb,
                       const ushort_t* __restrict__ xdblBC,
                       const ushort_t* __restrict__ xzbf, const ushort_t* __restrict__ u2bf,
                       ushort_t* __restrict__ ybf,
                       const float* __restrict__ A_log,
                       const float* __restrict__ D_param,
                       const ushort_t* __restrict__ hcarry)
{
    int idx = blockIdx.x * 256 + threadIdx.x;
    int p = idx & (NCHAN - 1);
    int c = idx >> 12;
    int b = p >> 11, e = p & (D_INNER - 1);
    float De = D_param[e];

    float An[D_STATE];
    {
        const float4* ar = reinterpret_cast<const float4*>(A_log + (size_t)e * D_STATE);
        #pragma unroll
        for (int q = 0; q < 4; ++q) {
            float4 a4 = ar[q];
            An[q * 4 + 0] = -__expf(a4.x);
            An[q * 4 + 1] = -__expf(a4.y);
            An[q * 4 + 2] = -__expf(a4.z);
            An[q * 4 + 3] = -__expf(a4.w);
        }
    }
    float h[D_STATE];
    {
        const ushort8v* hp = reinterpret_cast<const ushort8v*>(
            hcarry + ((size_t)p * NCHUNK + c) * D_STATE);
        ushort8v h0 = hp[0], h1 = hp[1];
        #pragma unroll
        for (int q = 0; q < 8; ++q) { h[q] = bf2f(h0[q]); h[8 + q] = bf2f(h1[q]); }
    }

    size_t rowbase = (size_t)b * SEQLEN + c * LCHUNK;
    #pragma unroll
    for (int j = 0; j < LCHUNK; ++j) {
        size_t row = rowbase + j;
        float dt = bf2f(dtb[row * D_INNER + e]);
        float u  = bf2f(u2bf[row * D_INNER + e]);
        float dtu = dt * u;
        const ushort8v* xr = reinterpret_cast<const ushort8v*>(xdblBC + row * 32);
        ushort8v b0 = xr[0], b1 = xr[1], c0v = xr[2], c1v = xr[3];
        float Bv[D_STATE], Cv[D_STATE];
        #pragma unroll
        for (int q = 0; q < 8; ++q) {
            Bv[q] = bf2f(b0[q]); Bv[8 + q] = bf2f(b1[q]);
            Cv[q] = bf2f(c0v[q]); Cv[8 + q] = bf2f(c1v[q]);
        }
        float y = 0.f;
        #pragma unroll
        for (int n = 0; n < D_STATE; ++n) {
            h[n] = __expf(dt * An[n]) * h[n] + dtu * Bv[n];
            y += h[n] * Cv[n];
        }
        float z  = bf2f(xzbf[row * (2 * D_INNER) + D_INNER + e]);
        float sz = z * fast_sigmoid(z);
        ybf[row * D_INNER + e] = f2bf((y + u * De) * sz);
    }
}

// ---------------------------------------------------------------------------
extern "C" void kernel_launch(void* const* d_in, const int* in_sizes, int n_in,
                              void* d_out, int out_size, void* d_ws, size_t ws_size,
                              hipStream_t stream)
{
    const float* x       = (const float*)d_in[0];
    const float* ln_g    = (const float*)d_in[1];
    const float* ln_b    = (const float*)d_in[2];
    const float* W_in    = (const float*)d_in[3];
    const float* conv_w  = (const float*)d_in[4];
    const float* conv_b  = (const float*)d_in[5];
    const float* W_xp    = (const float*)d_in[6];
    const float* W_dt    = (const float*)d_in[7];
    const float* b_dt    = (const float*)d_in[8];
    const float* A_log   = (const float*)d_in[9];
    const float* D_param = (const float*)d_in[10];
    const float* W_out   = (const float*)d_in[11];
    const float* res_sc  = (const float*)d_in[12];
    float* out = (float*)d_out;

    char* ws = (char*)d_ws;
    const size_t MB = 1024 * 1024;
    ushort_t* xzbf   = (ushort_t*)(ws);
    ushort_t* u2bf   = (ushort_t*)(ws + 16 * MB);
    ushort_t* dtb16  = (ushort_t*)(ws + 24 * MB);
    ushort_t* xdblBC = (ushort_t*)(ws + 32 * MB);
    ushort_t* hend   = (ushort_t*)(ws + 34 * MB);
    float*    sumdt  = (float*)(ws + 50 * MB);
    ushort_t* xnbf   = (ushort_t*)(ws + 51 * MB);
    ushort_t* WtIn   = (ushort_t*)(ws + 55 * MB);
    ushort_t* WtOut  = (ushort_t*)(ws + 63 * MB);
    ushort_t* WtXp   = (ushort_t*)(ws + 67 * MB);
    ushort_t* WtDt   = (ushort_t*)(ws + 67 * MB + 512 * 1024);
    ushort_t* ybf    = (ushort_t*)(ws + 68 * MB);
    float*    partsX = (float*)(ws + 76 * MB);

    // 0+1. mega-prologue: LayerNorm + all weight transposes (+WtXp pad)
    prologue_kernel<<<PRO_TOTAL, 256, 0, stream>>>(
        x, ln_g, ln_b, xnbf, W_in, WtIn, W_out, WtOut, W_xp, WtXp, W_dt, WtDt);

    // 2+3. xz = xn @ W_in fused with causal conv + SiLU (swizzled LDS)
    gemm_xz_conv<<<512, 256, 0, stream>>>(
        xnbf, WtIn, xzbf, conv_w, conv_b, u2bf);

    // 4. xdbl partials = u2 @ W_xp  split-K x8, BK=64 swizzled
    {
        dim3 grid(1, NROWS / 64, KSPLIT_XDBL);
        gemm_xdbl64<<<grid, 256, 0, stream>>>(u2bf, WtXp, partsX);
    }

    // 5. dt = softplus(sum(parts)[:, :64] @ W_dt + b_dt), single BK=64 iter
    {
        dim3 grid(D_INNER / 128, NROWS / 128);
        gemm_dt_fused<<<grid, 256, 0, stream>>>(partsX, WtDt, dtb16, b_dt, xdblBC);
    }

    // 6. chunked parallel scan (A: partials, B: inter-chunk, C: final+gate)
    scan_partial_kernel<<<(NCHAN * NCHUNK) / 256, 256, 0, stream>>>(
        dtb16, xdblBC, u2bf, A_log, hend, sumdt);
    scan_combine_kernel<<<NCHAN, 1024, 0, stream>>>(A_log, sumdt, hend);
    scan_final_kernel<<<(NCHAN * NCHUNK) / 256, 256, 0, stream>>>(
        dtb16, xdblBC, xzbf, u2bf, ybf, A_log, D_param, hend);

    // 7. out = x + rs * (y @ W_out)  64x64 BK=64 swizzled
    gemm_out64<<<512, 256, 0, stream>>>(ybf, WtOut, x, res_sc, out);
}

// Round 15
// 146.384 us; speedup vs baseline: 1.2846x; 1.2846x over previous
//
#include <hip/hip_runtime.h>
#include <hip/hip_bf16.h>

// Dims (compile-time constants from the reference)
#define D_MODEL 1024
#define D_STATE 16
#define D_CONV  4
#define D_INNER 2048
#define DT_RANK 64
#define BATCH   2
#define SEQLEN  1024
#define NROWS   (BATCH * SEQLEN)        // 2048
#define XDBL_W  (DT_RANK + 2 * D_STATE) // 96
#define NCHUNK  64                      // chunks per sequence
#define LCHUNK  16                      // steps per chunk
#define NCHAN   (BATCH * D_INNER)       // 4096 (b,e) channels
#define KSPLIT_XDBL 8

typedef unsigned short ushort_t;
typedef __attribute__((ext_vector_type(8))) short bf16x8;
typedef __attribute__((ext_vector_type(8))) unsigned short ushort8v;
typedef __attribute__((ext_vector_type(4))) float f32x4;

// fp32 -> bf16 (round-to-nearest-even), bit-level (deterministic)
__device__ __forceinline__ ushort_t f2bf(float f) {
    union { float f; unsigned u; } v; v.f = f;
    unsigned r = v.u + 0x7fffu + ((v.u >> 16) & 1u);
    return (ushort_t)(r >> 16);
}
__device__ __forceinline__ float bf2f(ushort_t h) {
    union { unsigned u; float f; } v; v.u = (unsigned)h << 16; return v.f;
}
__device__ __forceinline__ float fast_sigmoid(float z) {
    return __builtin_amdgcn_rcpf(1.f + __expf(-z));
}

// ---------------------------------------------------------------------------
// Mega-prologue: LayerNorm (2048 blocks) + 4 weight transpose-converts.
// ---------------------------------------------------------------------------
#define PRO_LN1   2048
#define PRO_TIN1  6144
#define PRO_TOUT1 8192
#define PRO_TXP1  8448
#define PRO_TOTAL 8576

__device__ __forceinline__ void transpose_job(const float* __restrict__ W,
                                              ushort_t* __restrict__ Wt,
                                              int R, int Creal,
                                              int cx, int ry, int tid,
                                              float t[32][33])
{
    int c0 = cx * 32, r0 = ry * 32;
    int tx = tid & 31, ty = tid >> 5;
    int col = c0 + tx;
    #pragma unroll
    for (int i = 0; i < 32; i += 8) {
        float v = (col < Creal) ? W[(size_t)(r0 + ty + i) * Creal + col] : 0.f;
        t[ty + i][tx] = v;
    }
    __syncthreads();
    #pragma unroll
    for (int i = 0; i < 32; i += 8)
        Wt[(size_t)(c0 + ty + i) * R + r0 + tx] = f2bf(t[tx][ty + i]);
}

__global__ __launch_bounds__(256)
void prologue_kernel(const float* __restrict__ x, const float* __restrict__ g,
                     const float* __restrict__ bb, ushort_t* __restrict__ xnbf,
                     const float* __restrict__ W_in, ushort_t* __restrict__ WtIn,
                     const float* __restrict__ W_out, ushort_t* __restrict__ WtOut,
                     const float* __restrict__ W_xp, ushort_t* __restrict__ WtXp,
                     const float* __restrict__ W_dt, ushort_t* __restrict__ WtDt)
{
    __shared__ float t[32][33];
    __shared__ float red[8];
    int bid = blockIdx.x;
    int tid = threadIdx.x;

    if (bid < PRO_LN1) {
        const float* xr = x + (size_t)bid * D_MODEL;
        float4 v = reinterpret_cast<const float4*>(xr)[tid];
        float s  = v.x + v.y + v.z + v.w;
        float ss = v.x * v.x + v.y * v.y + v.z * v.z + v.w * v.w;
        #pragma unroll
        for (int off = 32; off; off >>= 1) {
            s  += __shfl_down(s, off);
            ss += __shfl_down(ss, off);
        }
        int wid = tid >> 6, lane = tid & 63;
        if (lane == 0) { red[wid] = s; red[4 + wid] = ss; }
        __syncthreads();
        if (tid == 0) {
            float st = 0.f, sst = 0.f;
            #pragma unroll
            for (int i = 0; i < 4; ++i) { st += red[i]; sst += red[4 + i]; }
            red[0] = st; red[4] = sst;
        }
        __syncthreads();
        float mu  = red[0] * (1.f / D_MODEL);
        float var = red[4] * (1.f / D_MODEL) - mu * mu;
        float inv = rsqrtf(var + 1e-5f);
        float4 gv = reinterpret_cast<const float4*>(g)[tid];
        float4 bv = reinterpret_cast<const float4*>(bb)[tid];
        ushort4 o;
        o.x = f2bf((v.x - mu) * inv * gv.x + bv.x);
        o.y = f2bf((v.y - mu) * inv * gv.y + bv.y);
        o.z = f2bf((v.z - mu) * inv * gv.z + bv.z);
        o.w = f2bf((v.w - mu) * inv * gv.w + bv.w);
        reinterpret_cast<ushort4*>(xnbf + (size_t)bid * D_MODEL)[tid] = o;
    } else if (bid < PRO_TIN1) {
        int j = bid - PRO_LN1;
        transpose_job(W_in, WtIn, D_MODEL, 2 * D_INNER, j & 127, j >> 7, tid, t);
    } else if (bid < PRO_TOUT1) {
        int j = bid - PRO_TIN1;
        transpose_job(W_out, WtOut, D_INNER, D_MODEL, j & 31, j >> 5, tid, t);
    } else if (bid < PRO_TXP1) {
        int j = bid - PRO_TOUT1;
        transpose_job(W_xp, WtXp, D_INNER, XDBL_W, j & 3, j >> 2, tid, t);
    } else {
        int j = bid - PRO_TXP1;
        transpose_job(W_dt, WtDt, DT_RANK, D_INNER, j & 63, j >> 6, tid, t);
    }
}

// ---------------------------------------------------------------------------
// Global->LDS staging, width-16 async.
// ---------------------------------------------------------------------------
__device__ __forceinline__ void stage128x32(const ushort_t* __restrict__ gbase,
                                            size_t ld, ushort_t* ldsb, int tid)
{
    int l = tid & 63;
    int w = tid >> 6;
    int row = w * 16 + (l >> 2);
    int kg  = l & 3;
    char* lb = (char*)ldsb + w * 1024;
    const ushort_t* g0 = gbase + (size_t)row * ld + kg * 8;
    __builtin_amdgcn_global_load_lds(
        (const __attribute__((address_space(1))) unsigned*)g0,
        (__attribute__((address_space(3))) unsigned*)lb, 16, 0, 0);
    const ushort_t* g1 = g0 + (size_t)64 * ld;
    __builtin_amdgcn_global_load_lds(
        (const __attribute__((address_space(1))) unsigned*)g1,
        (__attribute__((address_space(3))) unsigned*)(lb + 4096), 16, 0, 0);
}

__device__ __forceinline__ void stage64x32(const ushort_t* __restrict__ gbase,
                                           size_t ld, ushort_t* ldsb, int tid)
{
    int l = tid & 63;
    int w = tid >> 6;
    int row = w * 16 + (l >> 2);
    int kg  = l & 3;
    char* lb = (char*)ldsb + w * 1024;
    const ushort_t* g0 = gbase + (size_t)row * ld + kg * 8;
    __builtin_amdgcn_global_load_lds(
        (const __attribute__((address_space(1))) unsigned*)g0,
        (__attribute__((address_space(3))) unsigned*)lb, 16, 0, 0);
}

// ---- T2 both-sides swizzle (rule #21): LDS dest stays lane-linear
// (base + l*16); the GLOBAL source chunk is pre-permuted gc=(l&7)^(row&7),
// and reads XOR the slot the same way. Each 8-lane group still loads one
// contiguous 128B global row (coalescing unchanged).

// 64 rows x 64 k bf16 (8KB), [64][64], swizzled.
__device__ __forceinline__ void stage64x64_swz(const ushort_t* __restrict__ gbase,
                                               size_t ld, ushort_t* ldsb, int tid)
{
    int l = tid & 63;
    int w = tid >> 6;
    int gc = (l & 7) ^ (l >> 3);               // row&7 == l>>3 here
    #pragma unroll
    for (int i = 0; i < 2; ++i) {
        int row = i * 32 + w * 8 + (l >> 3);
        const ushort_t* src = gbase + (size_t)row * ld + gc * 8;
        char* dst = (char*)ldsb + (i * 32 + w * 8) * 128;
        __builtin_amdgcn_global_load_lds(
            (const __attribute__((address_space(1))) unsigned*)src,
            (__attribute__((address_space(3))) unsigned*)dst, 16, 0, 0);
    }
}

// 128 rows x 64 k bf16 (16KB), [128][64], swizzled.
__device__ __forceinline__ void stage128x64_swz(const ushort_t* __restrict__ gbase,
                                                size_t ld, ushort_t* ldsb, int tid)
{
    int l = tid & 63;
    int w = tid >> 6;
    int gc = (l & 7) ^ (l >> 3);
    #pragma unroll
    for (int i = 0; i < 4; ++i) {
        int row = i * 32 + w * 8 + (l >> 3);
        const ushort_t* src = gbase + (size_t)row * ld + gc * 8;
        char* dst = (char*)ldsb + (i * 32 + w * 8) * 128;
        __builtin_amdgcn_global_load_lds(
            (const __attribute__((address_space(1))) unsigned*)src,
            (__attribute__((address_space(3))) unsigned*)dst, 16, 0, 0);
    }
}

// 16 rows x 64 k bf16 (2KB), [16][64], swizzled; waves 0-1 only.
__device__ __forceinline__ void stage16x64_swz(const ushort_t* __restrict__ gbase,
                                               size_t ld, ushort_t* ldsb, int tid)
{
    int l = tid & 63;
    int w = tid >> 6;
    if (w < 2) {
        int row = w * 8 + (l >> 3);
        int gc = (l & 7) ^ (l >> 3);
        const ushort_t* src = gbase + (size_t)row * ld + gc * 8;
        char* dst = (char*)ldsb + w * 8 * 128;
        __builtin_amdgcn_global_load_lds(
            (const __attribute__((address_space(1))) unsigned*)src,
            (__attribute__((address_space(3))) unsigned*)dst, 16, 0, 0);
    }
}

// ---------------------------------------------------------------------------
// Fused xz GEMM + causal conv + SiLU (swizzled LDS, rolling-window conv).
//   all tiles : acc = xn @ WtIn  (128x128, BK=64, XCD-swizzled grid)
//   u-tiles (bx<16): +16 boundary rows via extra MFMA fragment; epilogue
//     stages bf16 tile into T[144][130], 4-tap causal conv + bias + SiLU
//     with a 3-reg rolling window (1 LDS read per output), writes u2bf.
//   z-tiles (bx>=16): standard bf16 store into xzbf z-half.
// ---------------------------------------------------------------------------
__global__ __launch_bounds__(256)
void gemm_xz_conv(const ushort_t* __restrict__ A, const ushort_t* __restrict__ Bt,
                  ushort_t* __restrict__ xzbf,
                  const float* __restrict__ cw, const float* __restrict__ cb,
                  ushort_t* __restrict__ u2bf)
{
    // union: loop {As 8192, Bs 8192, As2 1024 ushorts}; epilogue T[144][130]
    __shared__ ushort_t smem[18720];
    ushort_t* As  = smem;
    ushort_t* Bs  = smem + 8192;
    ushort_t* As2 = smem + 16384;
    const int K = D_MODEL, N = 2 * D_INNER;
    int bid = blockIdx.x;                       // 512
    int swzb = ((bid & 7) << 6) + (bid >> 3);   // XCD-aware swizzle
    int bx = swzb & 31, by = swzb >> 5;
    bool isU = (bx < 16);
    int tid = threadIdx.x;
    int l = tid & 63, wid = tid >> 6;
    int wr = wid >> 1, wc = wid & 1;
    int row0 = by * 128, col0 = bx * 128;
    int l0 = row0 & (SEQLEN - 1);

    f32x4 acc[4][4];
    #pragma unroll
    for (int m = 0; m < 4; ++m)
        #pragma unroll
        for (int n = 0; n < 4; ++n)
            acc[m][n] = (f32x4){0.f, 0.f, 0.f, 0.f};
    f32x4 acc2[4];
    #pragma unroll
    for (int n = 0; n < 4; ++n) acc2[n] = (f32x4){0.f, 0.f, 0.f, 0.f};

    if (isU && l0 == 0)
        reinterpret_cast<ushort4*>(As2)[tid] = (ushort4){0, 0, 0, 0};

    const ushort_t* Ab  = A  + (size_t)row0 * K;
    const ushort_t* Ab2 = A  + (size_t)(row0 - 16) * K;   // valid iff l0 != 0
    const ushort_t* Bb  = Bt + (size_t)col0 * K;
    int arow = wr * 64 + (l & 15);
    int brow = wc * 64 + (l & 15);

    for (int k0 = 0; k0 < K; k0 += 64) {
        stage128x64_swz(Ab + k0, K, As, tid);
        stage128x64_swz(Bb + k0, K, Bs, tid);
        if (isU && l0 != 0) stage16x64_swz(Ab2 + k0, K, As2, tid);
        __syncthreads();
        #pragma unroll
        for (int ks = 0; ks < 2; ++ks) {
            int sw = (((ks * 4 + (l >> 4)) ^ (l & 7)) * 8);
            bf16x8 af[4], bfr[4];
            #pragma unroll
            for (int m = 0; m < 4; ++m)
                af[m] = *reinterpret_cast<const bf16x8*>(
                    &As[(arow + m * 16) * 64 + sw]);
            #pragma unroll
            for (int n = 0; n < 4; ++n)
                bfr[n] = *reinterpret_cast<const bf16x8*>(
                    &Bs[(brow + n * 16) * 64 + sw]);
            #pragma unroll
            for (int m = 0; m < 4; ++m)
                #pragma unroll
                for (int n = 0; n < 4; ++n)
                    acc[m][n] = __builtin_amdgcn_mfma_f32_16x16x32_bf16(
                        af[m], bfr[n], acc[m][n], 0, 0, 0);
            if (isU && wr == 0) {
                bf16x8 af2 = *reinterpret_cast<const bf16x8*>(
                    &As2[(l & 15) * 64 + sw]);
                #pragma unroll
                for (int n = 0; n < 4; ++n)
                    acc2[n] = __builtin_amdgcn_mfma_f32_16x16x32_bf16(
                        af2, bfr[n], acc2[n], 0, 0, 0);
            }
        }
        __syncthreads();
    }

    int ro = (l >> 4) * 4, co = l & 15;
    if (isU) {
        // ---- stage bf16 tile (+boundary rows) into T[144][130] ----
        #pragma unroll
        for (int m = 0; m < 4; ++m)
            #pragma unroll
            for (int n = 0; n < 4; ++n) {
                int c = wc * 64 + n * 16 + co;
                #pragma unroll
                for (int reg = 0; reg < 4; ++reg) {
                    int r = 16 + wr * 64 + m * 16 + ro + reg;
                    smem[r * 130 + c] = f2bf(acc[m][n][reg]);
                }
            }
        if (wr == 0) {
            #pragma unroll
            for (int n = 0; n < 4; ++n) {
                int c = wc * 64 + n * 16 + co;
                #pragma unroll
                for (int reg = 0; reg < 4; ++reg)
                    smem[(ro + reg) * 130 + c] = f2bf(acc2[n][reg]);
            }
        }
        __syncthreads();
        // ---- conv(4-tap causal) + bias + SiLU, rolling window -> u2bf ----
        int c = tid & 127;
        int half = tid >> 7;                   // 0 or 1
        int r0 = half * 64;
        int e = col0 + c;
        float4 w4 = *reinterpret_cast<const float4*>(cw + (size_t)e * 4);
        float cbv = cb[e];
        float h0 = bf2f(smem[(r0 + 13) * 130 + c]);
        float h1 = bf2f(smem[(r0 + 14) * 130 + c]);
        float h2 = bf2f(smem[(r0 + 15) * 130 + c]);
        #pragma unroll
        for (int j = 0; j < 64; ++j) {
            float cur = bf2f(smem[(r0 + 16 + j) * 130 + c]);
            float a = cbv + h0 * w4.x + h1 * w4.y + h2 * w4.z + cur * w4.w;
            u2bf[(size_t)(row0 + r0 + j) * D_INNER + e] = f2bf(a * fast_sigmoid(a));
            h0 = h1; h1 = h2; h2 = cur;
        }
    } else {
        // z-tile: standard bf16 store (gate input for scan_final)
        #pragma unroll
        for (int m = 0; m < 4; ++m) {
            #pragma unroll
            for (int n = 0; n < 4; ++n) {
                int c = col0 + wc * 64 + n * 16 + co;
                #pragma unroll
                for (int reg = 0; reg < 4; ++reg) {
                    int r = row0 + wr * 64 + m * 16 + ro + reg;
                    xzbf[(size_t)r * N + c] = f2bf(acc[m][n][reg]);
                }
            }
        }
    }
}

// ---------------------------------------------------------------------------
// Fused dt GEMM (BK=32, two phases — proven fast): A = sum_z partsX[z][:,0:64]
// (reduced in staging, bf16), B = WtDt[2048][64]^T.
// Epilogue: dt = softplus(acc + b_dt[col]) -> bf16.
// bx==0 blocks additionally emit xdblBC[2048][32] bf16 (B/C cols 64..96).
// ---------------------------------------------------------------------------
__global__ __launch_bounds__(256)
void gemm_dt_fused(const float* __restrict__ parts, const ushort_t* __restrict__ Bt,
                   ushort_t* __restrict__ dtb, const float* __restrict__ bias,
                   ushort_t* __restrict__ xdblBC)
{
    __shared__ ushort_t As[128 * 32];
    __shared__ ushort_t Bs[128 * 32];
    const int K = DT_RANK;   // 64
    int tid = threadIdx.x;
    int l = tid & 63, wid = tid >> 6;
    int wr = wid >> 1, wc = wid & 1;
    int row0 = blockIdx.y * 128, col0 = blockIdx.x * 128;

    // Side job (16 blocks): reduce B/C columns 64..96 to bf16 xdblBC.
    if (blockIdx.x == 0) {
        #pragma unroll
        for (int i = 0; i < 16; ++i) {
            int e2 = tid + 256 * i;             // 0..4095
            int rr = e2 >> 5, cc = e2 & 31;
            size_t r = (size_t)(row0 + rr);
            float s = 0.f;
            #pragma unroll
            for (int z = 0; z < KSPLIT_XDBL; ++z)
                s += parts[(size_t)z * NROWS * XDBL_W + r * XDBL_W + 64 + cc];
            xdblBC[r * 32 + cc] = f2bf(s);
        }
    }

    f32x4 acc[4][4];
    #pragma unroll
    for (int m = 0; m < 4; ++m)
        #pragma unroll
        for (int n = 0; n < 4; ++n)
            acc[m][n] = (f32x4){0.f, 0.f, 0.f, 0.f};

    const ushort_t* Bb = Bt + (size_t)col0 * K;
    int arow = wr * 64 + (l & 15);
    int brow = wc * 64 + (l & 15);
    int kb   = (l >> 4) * 8;

    #pragma unroll
    for (int k0 = 0; k0 < K; k0 += 32) {
        // A-stage: [128][32] = sum of 8 fp32 planes, converted to bf16.
        #pragma unroll
        for (int i = 0; i < 16; ++i) {
            int e2 = tid + 256 * i;
            int rr = e2 >> 5, cc = e2 & 31;
            size_t r = (size_t)(row0 + rr);
            float s = 0.f;
            #pragma unroll
            for (int z = 0; z < KSPLIT_XDBL; ++z)
                s += parts[(size_t)z * NROWS * XDBL_W + r * XDBL_W + k0 + cc];
            As[rr * 32 + cc] = f2bf(s);
        }
        stage128x32(Bb + k0, K, Bs, tid);
        __syncthreads();
        bf16x8 af[4], bfr[4];
        #pragma unroll
        for (int m = 0; m < 4; ++m)
            af[m] = *reinterpret_cast<const bf16x8*>(&As[(arow + m * 16) * 32 + kb]);
        #pragma unroll
        for (int n = 0; n < 4; ++n)
            bfr[n] = *reinterpret_cast<const bf16x8*>(&Bs[(brow + n * 16) * 32 + kb]);
        #pragma unroll
        for (int m = 0; m < 4; ++m)
            #pragma unroll
            for (int n = 0; n < 4; ++n)
                acc[m][n] = __builtin_amdgcn_mfma_f32_16x16x32_bf16(
                    af[m], bfr[n], acc[m][n], 0, 0, 0);
        __syncthreads();
    }

    int ro = (l >> 4) * 4, co = l & 15;
    #pragma unroll
    for (int m = 0; m < 4; ++m) {
        #pragma unroll
        for (int n = 0; n < 4; ++n) {
            int c = col0 + wc * 64 + n * 16 + co;
            float bdt = bias[c];
            #pragma unroll
            for (int reg = 0; reg < 4; ++reg) {
                int r = row0 + wr * 64 + m * 16 + ro + reg;
                float v = acc[m][n][reg] + bdt;
                v = (v > 20.f) ? v : __logf(1.f + __expf(v));   // softplus
                dtb[(size_t)r * D_INNER + c] = f2bf(v);
            }
        }
    }
}

// ---------------------------------------------------------------------------
// xdbl split-K GEMM, 64x128 tile, BK=32 (proven fast):
// parts[z][64-row-block][96] = u2 x WtXp^T over K-range.
// ---------------------------------------------------------------------------
__global__ __launch_bounds__(256)
void gemm_xdbl64(const ushort_t* __restrict__ A, const ushort_t* __restrict__ Bt,
                 float* __restrict__ parts)
{
    __shared__ ushort_t As[64 * 32];
    __shared__ ushort_t Bs[128 * 32];
    const int K = D_INNER;
    const int KS = D_INNER / KSPLIT_XDBL;      // 256
    int tid = threadIdx.x;
    int l = tid & 63, wid = tid >> 6;
    int wr = wid >> 1, wc = wid & 1;
    int row0 = blockIdx.y * 64;
    int kbeg = blockIdx.z * KS;

    f32x4 acc[2][4];
    #pragma unroll
    for (int m = 0; m < 2; ++m)
        #pragma unroll
        for (int n = 0; n < 4; ++n)
            acc[m][n] = (f32x4){0.f, 0.f, 0.f, 0.f};

    const ushort_t* Ab = A  + (size_t)row0 * K + kbeg;
    const ushort_t* Bb = Bt + kbeg;
    int arow = wr * 32 + (l & 15);
    int brow = wc * 64 + (l & 15);
    int kb   = (l >> 4) * 8;

    #pragma unroll
    for (int k0 = 0; k0 < KS; k0 += 32) {
        stage64x32(Ab + k0, K, As, tid);
        stage128x32(Bb + k0, K, Bs, tid);
        __syncthreads();
        bf16x8 af[2], bfr[4];
        #pragma unroll
        for (int m = 0; m < 2; ++m)
            af[m] = *reinterpret_cast<const bf16x8*>(&As[(arow + m * 16) * 32 + kb]);
        #pragma unroll
        for (int n = 0; n < 4; ++n)
            bfr[n] = *reinterpret_cast<const bf16x8*>(&Bs[(brow + n * 16) * 32 + kb]);
        #pragma unroll
        for (int m = 0; m < 2; ++m)
            #pragma unroll
            for (int n = 0; n < 4; ++n)
                acc[m][n] = __builtin_amdgcn_mfma_f32_16x16x32_bf16(
                    af[m], bfr[n], acc[m][n], 0, 0, 0);
        __syncthreads();
    }

    float* Cp = parts + (size_t)blockIdx.z * NROWS * XDBL_W;
    int ro = (l >> 4) * 4, co = l & 15;
    #pragma unroll
    for (int m = 0; m < 2; ++m) {
        #pragma unroll
        for (int n = 0; n < 4; ++n) {
            int c = wc * 64 + n * 16 + co;
            if (c >= XDBL_W) continue;
            #pragma unroll
            for (int reg = 0; reg < 4; ++reg) {
                int r = row0 + wr * 32 + m * 16 + ro + reg;
                Cp[(size_t)r * XDBL_W + c] = acc[m][n][reg];
            }
        }
    }
}

// ---------------------------------------------------------------------------
// out GEMM, 64x64 tile, BK=64, swizzled LDS: out = x + rs * (ybf x WtOut^T).
// ---------------------------------------------------------------------------
__global__ __launch_bounds__(256)
void gemm_out64(const ushort_t* __restrict__ A, const ushort_t* __restrict__ Bt,
                const float* __restrict__ x, const float* __restrict__ res_scale,
                float* __restrict__ out)
{
    __shared__ ushort_t As[64 * 64];
    __shared__ ushort_t Bs[64 * 64];
    const int K = D_INNER, N = D_MODEL;
    int bid = blockIdx.x;                       // 512
    int swzb = ((bid & 7) << 6) + (bid >> 3);
    int bx = swzb & 15, by = swzb >> 4;
    int tid = threadIdx.x;
    int l = tid & 63, wid = tid >> 6;
    int wr = wid >> 1, wc = wid & 1;
    int row0 = by * 64, col0 = bx * 64;

    f32x4 acc[2][2];
    #pragma unroll
    for (int m = 0; m < 2; ++m)
        #pragma unroll
        for (int n = 0; n < 2; ++n)
            acc[m][n] = (f32x4){0.f, 0.f, 0.f, 0.f};

    const ushort_t* Ab = A  + (size_t)row0 * K;
    const ushort_t* Bb = Bt + (size_t)col0 * K;
    int arow = wr * 32 + (l & 15);
    int brow = wc * 32 + (l & 15);

    for (int k0 = 0; k0 < K; k0 += 64) {
        stage64x64_swz(Ab + k0, K, As, tid);
        stage64x64_swz(Bb + k0, K, Bs, tid);
        __syncthreads();
        #pragma unroll
        for (int ks = 0; ks < 2; ++ks) {
            int sw = (((ks * 4 + (l >> 4)) ^ (l & 7)) * 8);
            bf16x8 af[2], bfr[2];
            #pragma unroll
            for (int m = 0; m < 2; ++m)
                af[m] = *reinterpret_cast<const bf16x8*>(
                    &As[(arow + m * 16) * 64 + sw]);
            #pragma unroll
            for (int n = 0; n < 2; ++n)
                bfr[n] = *reinterpret_cast<const bf16x8*>(
                    &Bs[(brow + n * 16) * 64 + sw]);
            #pragma unroll
            for (int m = 0; m < 2; ++m)
                #pragma unroll
                for (int n = 0; n < 2; ++n)
                    acc[m][n] = __builtin_amdgcn_mfma_f32_16x16x32_bf16(
                        af[m], bfr[n], acc[m][n], 0, 0, 0);
        }
        __syncthreads();
    }

    float rs = res_scale[0];
    int ro = (l >> 4) * 4, co = l & 15;
    #pragma unroll
    for (int m = 0; m < 2; ++m) {
        #pragma unroll
        for (int n = 0; n < 2; ++n) {
            int c = col0 + wc * 32 + n * 16 + co;
            #pragma unroll
            for (int reg = 0; reg < 4; ++reg) {
                int r = row0 + wr * 32 + m * 16 + ro + reg;
                out[(size_t)r * N + c] = x[(size_t)r * N + c] + rs * acc[m][n][reg];
            }
        }
    }
}

// ---------------------------------------------------------------------------
// Chunked scan, pass A: one thread per (channel, chunk); 16 states in regs.
// B row from bf16 xdblBC; hend written as bf16.
// ---------------------------------------------------------------------------
__global__ __launch_bounds__(256)
void scan_partial_kernel(const ushort_t* __restrict__ dtb,
                         const ushort_t* __restrict__ xdblBC,
                         const ushort_t* __restrict__ u2bf,
                         const float* __restrict__ A_log,
                         ushort_t* __restrict__ hend, float* __restrict__ sumdt_buf)
{
    int idx = blockIdx.x * 256 + threadIdx.x;   // 0 .. NCHAN*NCHUNK-1
    int p = idx & (NCHAN - 1);                  // channel (64 consecutive/wave)
    int c = idx >> 12;                          // chunk
    int b = p >> 11, e = p & (D_INNER - 1);

    float An[D_STATE];
    {
        const float4* ar = reinterpret_cast<const float4*>(A_log + (size_t)e * D_STATE);
        #pragma unroll
        for (int q = 0; q < 4; ++q) {
            float4 a4 = ar[q];
            An[q * 4 + 0] = -__expf(a4.x);
            An[q * 4 + 1] = -__expf(a4.y);
            An[q * 4 + 2] = -__expf(a4.z);
            An[q * 4 + 3] = -__expf(a4.w);
        }
    }
    float h[D_STATE];
    #pragma unroll
    for (int n = 0; n < D_STATE; ++n) h[n] = 0.f;
    float sdt = 0.f;

    size_t rowbase = (size_t)b * SEQLEN + c * LCHUNK;
    #pragma unroll
    for (int j = 0; j < LCHUNK; ++j) {
        size_t row = rowbase + j;
        float dt = bf2f(dtb[row * D_INNER + e]);
        float u  = bf2f(u2bf[row * D_INNER + e]);
        float dtu = dt * u;
        sdt += dt;
        const ushort8v* xr = reinterpret_cast<const ushort8v*>(xdblBC + row * 32);
        ushort8v b0 = xr[0], b1 = xr[1];
        float Bv[D_STATE];
        #pragma unroll
        for (int q = 0; q < 8; ++q) { Bv[q] = bf2f(b0[q]); Bv[8 + q] = bf2f(b1[q]); }
        #pragma unroll
        for (int n = 0; n < D_STATE; ++n)
            h[n] = __expf(dt * An[n]) * h[n] + dtu * Bv[n];
    }

    ushort8v o0, o1;
    #pragma unroll
    for (int q = 0; q < 8; ++q) { o0[q] = f2bf(h[q]); o1[q] = f2bf(h[8 + q]); }
    ushort8v* hp = reinterpret_cast<ushort8v*>(hend + ((size_t)p * NCHUNK + c) * D_STATE);
    hp[0] = o0; hp[1] = o1;
    sumdt_buf[p * NCHUNK + c] = sdt;
}

// ---------------------------------------------------------------------------
// Pass B: per-channel inter-chunk Hillis-Steele scan (fp32 in LDS);
// reads bf16 hend, writes bf16 exclusive carry in place.
// ---------------------------------------------------------------------------
__global__ __launch_bounds__(1024)
void scan_combine_kernel(const float* __restrict__ A_log,
                         const float* __restrict__ sumdt_buf,
                         ushort_t* __restrict__ hend /* in: hend, out: hcarry */)
{
    __shared__ float Ps[NCHUNK][D_STATE];
    __shared__ float Hs[NCHUNK][D_STATE];
    int tid = threadIdx.x;
    int c = tid >> 4, n = tid & 15;
    int p = blockIdx.x;
    int e = p & (D_INNER - 1);
    float An = -__expf(A_log[e * D_STATE + n]);
    float P = __expf(An * sumdt_buf[p * NCHUNK + c]);
    float H = bf2f(hend[(size_t)p * (NCHUNK * D_STATE) + c * D_STATE + n]);
    Ps[c][n] = P; Hs[c][n] = H;
    __syncthreads();
    #pragma unroll
    for (int d = 1; d < NCHUNK; d <<= 1) {
        float Pl = 1.f, Hl = 0.f;
        if (c >= d) { Pl = Ps[c - d][n]; Hl = Hs[c - d][n]; }
        __syncthreads();
        H = P * Hl + H;   // (P,H) o (Pl,Hl)
        P = P * Pl;
        Ps[c][n] = P; Hs[c][n] = H;
        __syncthreads();
    }
    float carry = (c == 0) ? 0.f : Hs[c - 1][n];
    hend[(size_t)p * (NCHUNK * D_STATE) + c * D_STATE + n] = f2bf(carry);
}

// ---------------------------------------------------------------------------
// Pass C: one thread per (channel, chunk), seeded with bf16 carry; in-register
// dot with C row; fused D-skip + SiLU(z) gate; writes y as bf16.
// ---------------------------------------------------------------------------
__global__ __launch_bounds__(256)
void scan_final_kernel(const ushort_t* __restrict__ dtb,
                       const ushort_t* __restrict__ xdblBC,
                       const ushort_t* __restrict__ xzbf, const ushort_t* __restrict__ u2bf,
                       ushort_t* __restrict__ ybf,
                       const float* __restrict__ A_log,
                       const float* __restrict__ D_param,
                       const ushort_t* __restrict__ hcarry)
{
    int idx = blockIdx.x * 256 + threadIdx.x;
    int p = idx & (NCHAN - 1);
    int c = idx >> 12;
    int b = p >> 11, e = p & (D_INNER - 1);
    float De = D_param[e];

    float An[D_STATE];
    {
        const float4* ar = reinterpret_cast<const float4*>(A_log + (size_t)e * D_STATE);
        #pragma unroll
        for (int q = 0; q < 4; ++q) {
            float4 a4 = ar[q];
            An[q * 4 + 0] = -__expf(a4.x);
            An[q * 4 + 1] = -__expf(a4.y);
            An[q * 4 + 2] = -__expf(a4.z);
            An[q * 4 + 3] = -__expf(a4.w);
        }
    }
    float h[D_STATE];
    {
        const ushort8v* hp = reinterpret_cast<const ushort8v*>(
            hcarry + ((size_t)p * NCHUNK + c) * D_STATE);
        ushort8v h0 = hp[0], h1 = hp[1];
        #pragma unroll
        for (int q = 0; q < 8; ++q) { h[q] = bf2f(h0[q]); h[8 + q] = bf2f(h1[q]); }
    }

    size_t rowbase = (size_t)b * SEQLEN + c * LCHUNK;
    #pragma unroll
    for (int j = 0; j < LCHUNK; ++j) {
        size_t row = rowbase + j;
        float dt = bf2f(dtb[row * D_INNER + e]);
        float u  = bf2f(u2bf[row * D_INNER + e]);
        float dtu = dt * u;
        const ushort8v* xr = reinterpret_cast<const ushort8v*>(xdblBC + row * 32);
        ushort8v b0 = xr[0], b1 = xr[1], c0v = xr[2], c1v = xr[3];
        float Bv[D_STATE], Cv[D_STATE];
        #pragma unroll
        for (int q = 0; q < 8; ++q) {
            Bv[q] = bf2f(b0[q]); Bv[8 + q] = bf2f(b1[q]);
            Cv[q] = bf2f(c0v[q]); Cv[8 + q] = bf2f(c1v[q]);
        }
        float y = 0.f;
        #pragma unroll
        for (int n = 0; n < D_STATE; ++n) {
            h[n] = __expf(dt * An[n]) * h[n] + dtu * Bv[n];
            y += h[n] * Cv[n];
        }
        float z  = bf2f(xzbf[row * (2 * D_INNER) + D_INNER + e]);
        float sz = z * fast_sigmoid(z);
        ybf[row * D_INNER + e] = f2bf((y + u * De) * sz);
    }
}

// ---------------------------------------------------------------------------
extern "C" void kernel_launch(void* const* d_in, const int* in_sizes, int n_in,
                              void* d_out, int out_size, void* d_ws, size_t ws_size,
                              hipStream_t stream)
{
    const float* x       = (const float*)d_in[0];
    const float* ln_g    = (const float*)d_in[1];
    const float* ln_b    = (const float*)d_in[2];
    const float* W_in    = (const float*)d_in[3];
    const float* conv_w  = (const float*)d_in[4];
    const float* conv_b  = (const float*)d_in[5];
    const float* W_xp    = (const float*)d_in[6];
    const float* W_dt    = (const float*)d_in[7];
    const float* b_dt    = (const float*)d_in[8];
    const float* A_log   = (const float*)d_in[9];
    const float* D_param = (const float*)d_in[10];
    const float* W_out   = (const float*)d_in[11];
    const float* res_sc  = (const float*)d_in[12];
    float* out = (float*)d_out;

    char* ws = (char*)d_ws;
    const size_t MB = 1024 * 1024;
    // Workspace (peak 82 MB):
    //   xzbf    [0,16M)      2048x4096 bf16 (only z cols 2048-4095 written)
    //   u2bf    [16M,24M)    2048x2048 bf16 (written by fused xz+conv)
    //   dtb16   [24M,32M)    2048x2048 bf16 (softplus'd dt)
    //   xdblBC  [32M,32.125M) 2048x32 bf16 (B cols 64..80, C cols 80..96)
    //   hend    [34M,42M)    4096x64x16 bf16 (carry in place)
    //   sumdt   [50M,51M)    4096x64 fp32
    //   xnbf    [51M,55M)    2048x1024 bf16
    //   WtIn    [55M,63M)    4096x1024 bf16
    //   WtOut   [63M,67M)    1024x2048 bf16
    //   WtXp    [67M,67.5M)  128x2048 bf16 (rows 96..127 zeroed via col guard)
    //   WtDt    [67.5M,68M)  2048x64 bf16
    //   ybf     [68M,76M)    2048x2048 bf16
    //   partsX  [76M,82M)    8x2048x96 fp32
    ushort_t* xzbf   = (ushort_t*)(ws);
    ushort_t* u2bf   = (ushort_t*)(ws + 16 * MB);
    ushort_t* dtb16  = (ushort_t*)(ws + 24 * MB);
    ushort_t* xdblBC = (ushort_t*)(ws + 32 * MB);
    ushort_t* hend   = (ushort_t*)(ws + 34 * MB);
    float*    sumdt  = (float*)(ws + 50 * MB);
    ushort_t* xnbf   = (ushort_t*)(ws + 51 * MB);
    ushort_t* WtIn   = (ushort_t*)(ws + 55 * MB);
    ushort_t* WtOut  = (ushort_t*)(ws + 63 * MB);
    ushort_t* WtXp   = (ushort_t*)(ws + 67 * MB);
    ushort_t* WtDt   = (ushort_t*)(ws + 67 * MB + 512 * 1024);
    ushort_t* ybf    = (ushort_t*)(ws + 68 * MB);
    float*    partsX = (float*)(ws + 76 * MB);

    // 0+1. mega-prologue: LayerNorm + all weight transposes (+WtXp pad)
    prologue_kernel<<<PRO_TOTAL, 256, 0, stream>>>(
        x, ln_g, ln_b, xnbf, W_in, WtIn, W_out, WtOut, W_xp, WtXp, W_dt, WtDt);

    // 2+3. xz = xn @ W_in fused with causal conv + SiLU (swizzled LDS)
    gemm_xz_conv<<<512, 256, 0, stream>>>(
        xnbf, WtIn, xzbf, conv_w, conv_b, u2bf);

    // 4. xdbl partials = u2 @ W_xp  [2048 x 96, K=2048]  64-row-tile split-K x8
    {
        dim3 grid(1, NROWS / 64, KSPLIT_XDBL);
        gemm_xdbl64<<<grid, 256, 0, stream>>>(u2bf, WtXp, partsX);
    }

    // 5. dt = softplus(sum(parts)[:, :64] @ W_dt + b_dt)  (fused reduce+GEMM);
    //    bx==0 blocks also emit xdblBC bf16 (B/C cols).
    {
        dim3 grid(D_INNER / 128, NROWS / 128);
        gemm_dt_fused<<<grid, 256, 0, stream>>>(partsX, WtDt, dtb16, b_dt, xdblBC);
    }

    // 6. chunked parallel scan (A: partials, B: inter-chunk, C: final+gate)
    scan_partial_kernel<<<(NCHAN * NCHUNK) / 256, 256, 0, stream>>>(
        dtb16, xdblBC, u2bf, A_log, hend, sumdt);
    scan_combine_kernel<<<NCHAN, 1024, 0, stream>>>(A_log, sumdt, hend);
    scan_final_kernel<<<(NCHAN * NCHUNK) / 256, 256, 0, stream>>>(
        dtb16, xdblBC, xzbf, u2bf, ybf, A_log, D_param, hend);

    // 7. out = x + rs * (y @ W_out)  [2048 x 1024, K=2048]  64x64 BK=64 swz
    gemm_out64<<<512, 256, 0, stream>>>(ybf, WtOut, x, res_sc, out);
}

// Round 16
// 141.179 us; speedup vs baseline: 1.3319x; 1.0369x over previous
//
#include <hip/hip_runtime.h>
#include <hip/hip_bf16.h>

// Dims (compile-time constants from the reference)
#define D_MODEL 1024
#define D_STATE 16
#define D_CONV  4
#define D_INNER 2048
#define DT_RANK 64
#define BATCH   2
#define SEQLEN  1024
#define NROWS   (BATCH * SEQLEN)        // 2048
#define XDBL_W  (DT_RANK + 2 * D_STATE) // 96
#define NCHUNK  64                      // chunks per sequence
#define LCHUNK  16                      // steps per chunk
#define NCHAN   (BATCH * D_INNER)       // 4096 (b,e) channels
#define KSPLIT_XDBL 8

typedef unsigned short ushort_t;
typedef __attribute__((ext_vector_type(8))) short bf16x8;
typedef __attribute__((ext_vector_type(8))) unsigned short ushort8v;
typedef __attribute__((ext_vector_type(4))) float f32x4;

// fp32 -> bf16 (round-to-nearest-even), bit-level (deterministic)
__device__ __forceinline__ ushort_t f2bf(float f) {
    union { float f; unsigned u; } v; v.f = f;
    unsigned r = v.u + 0x7fffu + ((v.u >> 16) & 1u);
    return (ushort_t)(r >> 16);
}
__device__ __forceinline__ float bf2f(ushort_t h) {
    union { unsigned u; float f; } v; v.u = (unsigned)h << 16; return v.f;
}
__device__ __forceinline__ float fast_sigmoid(float z) {
    return __builtin_amdgcn_rcpf(1.f + __expf(-z));
}

// ---------------------------------------------------------------------------
// Mega-prologue: LayerNorm (2048 blocks) + 4 weight transpose-converts.
// ---------------------------------------------------------------------------
#define PRO_LN1   2048
#define PRO_TIN1  6144
#define PRO_TOUT1 8192
#define PRO_TXP1  8448
#define PRO_TOTAL 8576

__device__ __forceinline__ void transpose_job(const float* __restrict__ W,
                                              ushort_t* __restrict__ Wt,
                                              int R, int Creal,
                                              int cx, int ry, int tid,
                                              float t[32][33])
{
    int c0 = cx * 32, r0 = ry * 32;
    int tx = tid & 31, ty = tid >> 5;
    int col = c0 + tx;
    #pragma unroll
    for (int i = 0; i < 32; i += 8) {
        float v = (col < Creal) ? W[(size_t)(r0 + ty + i) * Creal + col] : 0.f;
        t[ty + i][tx] = v;
    }
    __syncthreads();
    #pragma unroll
    for (int i = 0; i < 32; i += 8)
        Wt[(size_t)(c0 + ty + i) * R + r0 + tx] = f2bf(t[tx][ty + i]);
}

__global__ __launch_bounds__(256)
void prologue_kernel(const float* __restrict__ x, const float* __restrict__ g,
                     const float* __restrict__ bb, ushort_t* __restrict__ xnbf,
                     const float* __restrict__ W_in, ushort_t* __restrict__ WtIn,
                     const float* __restrict__ W_out, ushort_t* __restrict__ WtOut,
                     const float* __restrict__ W_xp, ushort_t* __restrict__ WtXp,
                     const float* __restrict__ W_dt, ushort_t* __restrict__ WtDt)
{
    __shared__ float t[32][33];
    __shared__ float red[8];
    int bid = blockIdx.x;
    int tid = threadIdx.x;

    if (bid < PRO_LN1) {
        const float* xr = x + (size_t)bid * D_MODEL;
        float4 v = reinterpret_cast<const float4*>(xr)[tid];
        float s  = v.x + v.y + v.z + v.w;
        float ss = v.x * v.x + v.y * v.y + v.z * v.z + v.w * v.w;
        #pragma unroll
        for (int off = 32; off; off >>= 1) {
            s  += __shfl_down(s, off);
            ss += __shfl_down(ss, off);
        }
        int wid = tid >> 6, lane = tid & 63;
        if (lane == 0) { red[wid] = s; red[4 + wid] = ss; }
        __syncthreads();
        if (tid == 0) {
            float st = 0.f, sst = 0.f;
            #pragma unroll
            for (int i = 0; i < 4; ++i) { st += red[i]; sst += red[4 + i]; }
            red[0] = st; red[4] = sst;
        }
        __syncthreads();
        float mu  = red[0] * (1.f / D_MODEL);
        float var = red[4] * (1.f / D_MODEL) - mu * mu;
        float inv = rsqrtf(var + 1e-5f);
        float4 gv = reinterpret_cast<const float4*>(g)[tid];
        float4 bv = reinterpret_cast<const float4*>(bb)[tid];
        ushort4 o;
        o.x = f2bf((v.x - mu) * inv * gv.x + bv.x);
        o.y = f2bf((v.y - mu) * inv * gv.y + bv.y);
        o.z = f2bf((v.z - mu) * inv * gv.z + bv.z);
        o.w = f2bf((v.w - mu) * inv * gv.w + bv.w);
        reinterpret_cast<ushort4*>(xnbf + (size_t)bid * D_MODEL)[tid] = o;
    } else if (bid < PRO_TIN1) {
        int j = bid - PRO_LN1;
        transpose_job(W_in, WtIn, D_MODEL, 2 * D_INNER, j & 127, j >> 7, tid, t);
    } else if (bid < PRO_TOUT1) {
        int j = bid - PRO_TIN1;
        transpose_job(W_out, WtOut, D_INNER, D_MODEL, j & 31, j >> 5, tid, t);
    } else if (bid < PRO_TXP1) {
        int j = bid - PRO_TOUT1;
        transpose_job(W_xp, WtXp, D_INNER, XDBL_W, j & 3, j >> 2, tid, t);
    } else {
        int j = bid - PRO_TXP1;
        transpose_job(W_dt, WtDt, DT_RANK, D_INNER, j & 63, j >> 6, tid, t);
    }
}

// ---------------------------------------------------------------------------
// Global->LDS staging, width-16 async.
// ---------------------------------------------------------------------------
__device__ __forceinline__ void stage128x32(const ushort_t* __restrict__ gbase,
                                            size_t ld, ushort_t* ldsb, int tid)
{
    int l = tid & 63;
    int w = tid >> 6;
    int row = w * 16 + (l >> 2);
    int kg  = l & 3;
    char* lb = (char*)ldsb + w * 1024;
    const ushort_t* g0 = gbase + (size_t)row * ld + kg * 8;
    __builtin_amdgcn_global_load_lds(
        (const __attribute__((address_space(1))) unsigned*)g0,
        (__attribute__((address_space(3))) unsigned*)lb, 16, 0, 0);
    const ushort_t* g1 = g0 + (size_t)64 * ld;
    __builtin_amdgcn_global_load_lds(
        (const __attribute__((address_space(1))) unsigned*)g1,
        (__attribute__((address_space(3))) unsigned*)(lb + 4096), 16, 0, 0);
}

__device__ __forceinline__ void stage64x32(const ushort_t* __restrict__ gbase,
                                           size_t ld, ushort_t* ldsb, int tid)
{
    int l = tid & 63;
    int w = tid >> 6;
    int row = w * 16 + (l >> 2);
    int kg  = l & 3;
    char* lb = (char*)ldsb + w * 1024;
    const ushort_t* g0 = gbase + (size_t)row * ld + kg * 8;
    __builtin_amdgcn_global_load_lds(
        (const __attribute__((address_space(1))) unsigned*)g0,
        (__attribute__((address_space(3))) unsigned*)lb, 16, 0, 0);
}

// ---- T2 both-sides swizzle (rule #21): LDS dest stays lane-linear
// (base + l*16); the GLOBAL source chunk is pre-permuted gc=(l&7)^(row&7),
// and reads XOR the slot the same way. Each 8-lane group still loads one
// contiguous 128B global row (coalescing unchanged).

// 64 rows x 64 k bf16 (8KB), [64][64], swizzled.
__device__ __forceinline__ void stage64x64_swz(const ushort_t* __restrict__ gbase,
                                               size_t ld, ushort_t* ldsb, int tid)
{
    int l = tid & 63;
    int w = tid >> 6;
    int gc = (l & 7) ^ (l >> 3);               // row&7 == l>>3 here
    #pragma unroll
    for (int i = 0; i < 2; ++i) {
        int row = i * 32 + w * 8 + (l >> 3);
        const ushort_t* src = gbase + (size_t)row * ld + gc * 8;
        char* dst = (char*)ldsb + (i * 32 + w * 8) * 128;
        __builtin_amdgcn_global_load_lds(
            (const __attribute__((address_space(1))) unsigned*)src,
            (__attribute__((address_space(3))) unsigned*)dst, 16, 0, 0);
    }
}

// 128 rows x 64 k bf16 (16KB), [128][64], swizzled.
__device__ __forceinline__ void stage128x64_swz(const ushort_t* __restrict__ gbase,
                                                size_t ld, ushort_t* ldsb, int tid)
{
    int l = tid & 63;
    int w = tid >> 6;
    int gc = (l & 7) ^ (l >> 3);
    #pragma unroll
    for (int i = 0; i < 4; ++i) {
        int row = i * 32 + w * 8 + (l >> 3);
        const ushort_t* src = gbase + (size_t)row * ld + gc * 8;
        char* dst = (char*)ldsb + (i * 32 + w * 8) * 128;
        __builtin_amdgcn_global_load_lds(
            (const __attribute__((address_space(1))) unsigned*)src,
            (__attribute__((address_space(3))) unsigned*)dst, 16, 0, 0);
    }
}

// 16 rows x 64 k bf16 (2KB), [16][64], swizzled; waves 0-1 only.
__device__ __forceinline__ void stage16x64_swz(const ushort_t* __restrict__ gbase,
                                               size_t ld, ushort_t* ldsb, int tid)
{
    int l = tid & 63;
    int w = tid >> 6;
    if (w < 2) {
        int row = w * 8 + (l >> 3);
        int gc = (l & 7) ^ (l >> 3);
        const ushort_t* src = gbase + (size_t)row * ld + gc * 8;
        char* dst = (char*)ldsb + w * 8 * 128;
        __builtin_amdgcn_global_load_lds(
            (const __attribute__((address_space(1))) unsigned*)src,
            (__attribute__((address_space(3))) unsigned*)dst, 16, 0, 0);
    }
}

// ---------------------------------------------------------------------------
// Fused xz GEMM + causal conv + SiLU (swizzled LDS, rolling-window conv).
//   all tiles : acc = xn @ WtIn  (128x128, BK=64, XCD-swizzled grid)
//   u-tiles (bx<16): +16 boundary rows via extra MFMA fragment; epilogue
//     stages bf16 tile into T[144][130], 4-tap causal conv + bias + SiLU
//     with a 3-reg rolling window (1 LDS read per output), writes u2bf.
//   z-tiles (bx>=16): standard bf16 store into xzbf z-half.
// ---------------------------------------------------------------------------
__global__ __launch_bounds__(256)
void gemm_xz_conv(const ushort_t* __restrict__ A, const ushort_t* __restrict__ Bt,
                  ushort_t* __restrict__ xzbf,
                  const float* __restrict__ cw, const float* __restrict__ cb,
                  ushort_t* __restrict__ u2bf)
{
    // union: loop {As 8192, Bs 8192, As2 1024 ushorts}; epilogue T[144][130]
    __shared__ ushort_t smem[18720];
    ushort_t* As  = smem;
    ushort_t* Bs  = smem + 8192;
    ushort_t* As2 = smem + 16384;
    const int K = D_MODEL, N = 2 * D_INNER;
    int bid = blockIdx.x;                       // 512
    int swzb = ((bid & 7) << 6) + (bid >> 3);   // XCD-aware swizzle
    int bx = swzb & 31, by = swzb >> 5;
    bool isU = (bx < 16);
    int tid = threadIdx.x;
    int l = tid & 63, wid = tid >> 6;
    int wr = wid >> 1, wc = wid & 1;
    int row0 = by * 128, col0 = bx * 128;
    int l0 = row0 & (SEQLEN - 1);

    f32x4 acc[4][4];
    #pragma unroll
    for (int m = 0; m < 4; ++m)
        #pragma unroll
        for (int n = 0; n < 4; ++n)
            acc[m][n] = (f32x4){0.f, 0.f, 0.f, 0.f};
    f32x4 acc2[4];
    #pragma unroll
    for (int n = 0; n < 4; ++n) acc2[n] = (f32x4){0.f, 0.f, 0.f, 0.f};

    if (isU && l0 == 0)
        reinterpret_cast<ushort4*>(As2)[tid] = (ushort4){0, 0, 0, 0};

    const ushort_t* Ab  = A  + (size_t)row0 * K;
    const ushort_t* Ab2 = A  + (size_t)(row0 - 16) * K;   // valid iff l0 != 0
    const ushort_t* Bb  = Bt + (size_t)col0 * K;
    int arow = wr * 64 + (l & 15);
    int brow = wc * 64 + (l & 15);

    for (int k0 = 0; k0 < K; k0 += 64) {
        stage128x64_swz(Ab + k0, K, As, tid);
        stage128x64_swz(Bb + k0, K, Bs, tid);
        if (isU && l0 != 0) stage16x64_swz(Ab2 + k0, K, As2, tid);
        __syncthreads();
        #pragma unroll
        for (int ks = 0; ks < 2; ++ks) {
            int sw = (((ks * 4 + (l >> 4)) ^ (l & 7)) * 8);
            bf16x8 af[4], bfr[4];
            #pragma unroll
            for (int m = 0; m < 4; ++m)
                af[m] = *reinterpret_cast<const bf16x8*>(
                    &As[(arow + m * 16) * 64 + sw]);
            #pragma unroll
            for (int n = 0; n < 4; ++n)
                bfr[n] = *reinterpret_cast<const bf16x8*>(
                    &Bs[(brow + n * 16) * 64 + sw]);
            #pragma unroll
            for (int m = 0; m < 4; ++m)
                #pragma unroll
                for (int n = 0; n < 4; ++n)
                    acc[m][n] = __builtin_amdgcn_mfma_f32_16x16x32_bf16(
                        af[m], bfr[n], acc[m][n], 0, 0, 0);
            if (isU && wr == 0) {
                bf16x8 af2 = *reinterpret_cast<const bf16x8*>(
                    &As2[(l & 15) * 64 + sw]);
                #pragma unroll
                for (int n = 0; n < 4; ++n)
                    acc2[n] = __builtin_amdgcn_mfma_f32_16x16x32_bf16(
                        af2, bfr[n], acc2[n], 0, 0, 0);
            }
        }
        __syncthreads();
    }

    int ro = (l >> 4) * 4, co = l & 15;
    if (isU) {
        // ---- stage bf16 tile (+boundary rows) into T[144][130] ----
        #pragma unroll
        for (int m = 0; m < 4; ++m)
            #pragma unroll
            for (int n = 0; n < 4; ++n) {
                int c = wc * 64 + n * 16 + co;
                #pragma unroll
                for (int reg = 0; reg < 4; ++reg) {
                    int r = 16 + wr * 64 + m * 16 + ro + reg;
                    smem[r * 130 + c] = f2bf(acc[m][n][reg]);
                }
            }
        if (wr == 0) {
            #pragma unroll
            for (int n = 0; n < 4; ++n) {
                int c = wc * 64 + n * 16 + co;
                #pragma unroll
                for (int reg = 0; reg < 4; ++reg)
                    smem[(ro + reg) * 130 + c] = f2bf(acc2[n][reg]);
            }
        }
        __syncthreads();
        // ---- conv(4-tap causal) + bias + SiLU, rolling window -> u2bf ----
        int c = tid & 127;
        int half = tid >> 7;                   // 0 or 1
        int r0 = half * 64;
        int e = col0 + c;
        float4 w4 = *reinterpret_cast<const float4*>(cw + (size_t)e * 4);
        float cbv = cb[e];
        float h0 = bf2f(smem[(r0 + 13) * 130 + c]);
        float h1 = bf2f(smem[(r0 + 14) * 130 + c]);
        float h2 = bf2f(smem[(r0 + 15) * 130 + c]);
        #pragma unroll
        for (int j = 0; j < 64; ++j) {
            float cur = bf2f(smem[(r0 + 16 + j) * 130 + c]);
            float a = cbv + h0 * w4.x + h1 * w4.y + h2 * w4.z + cur * w4.w;
            u2bf[(size_t)(row0 + r0 + j) * D_INNER + e] = f2bf(a * fast_sigmoid(a));
            h0 = h1; h1 = h2; h2 = cur;
        }
    } else {
        // z-tile: standard bf16 store (gate input for scan_final)
        #pragma unroll
        for (int m = 0; m < 4; ++m) {
            #pragma unroll
            for (int n = 0; n < 4; ++n) {
                int c = col0 + wc * 64 + n * 16 + co;
                #pragma unroll
                for (int reg = 0; reg < 4; ++reg) {
                    int r = row0 + wr * 64 + m * 16 + ro + reg;
                    xzbf[(size_t)r * N + c] = f2bf(acc[m][n][reg]);
                }
            }
        }
    }
}

// ---------------------------------------------------------------------------
// Fused dt GEMM (BK=32, two phases — proven fast): A = sum_z partsX[z][:,0:64]
// (reduced in staging, bf16), B = WtDt[2048][64]^T.
// Epilogue: dt = softplus(acc + b_dt[col]) -> bf16.
// bx==0 blocks additionally emit xdblBC[2048][32] bf16 (B/C cols 64..96).
// ---------------------------------------------------------------------------
__global__ __launch_bounds__(256)
void gemm_dt_fused(const float* __restrict__ parts, const ushort_t* __restrict__ Bt,
                   ushort_t* __restrict__ dtb, const float* __restrict__ bias,
                   ushort_t* __restrict__ xdblBC)
{
    __shared__ ushort_t As[128 * 32];
    __shared__ ushort_t Bs[128 * 32];
    const int K = DT_RANK;   // 64
    int tid = threadIdx.x;
    int l = tid & 63, wid = tid >> 6;
    int wr = wid >> 1, wc = wid & 1;
    int row0 = blockIdx.y * 128, col0 = blockIdx.x * 128;

    // Side job (16 blocks): reduce B/C columns 64..96 to bf16 xdblBC.
    if (blockIdx.x == 0) {
        #pragma unroll
        for (int i = 0; i < 16; ++i) {
            int e2 = tid + 256 * i;             // 0..4095
            int rr = e2 >> 5, cc = e2 & 31;
            size_t r = (size_t)(row0 + rr);
            float s = 0.f;
            #pragma unroll
            for (int z = 0; z < KSPLIT_XDBL; ++z)
                s += parts[(size_t)z * NROWS * XDBL_W + r * XDBL_W + 64 + cc];
            xdblBC[r * 32 + cc] = f2bf(s);
        }
    }

    f32x4 acc[4][4];
    #pragma unroll
    for (int m = 0; m < 4; ++m)
        #pragma unroll
        for (int n = 0; n < 4; ++n)
            acc[m][n] = (f32x4){0.f, 0.f, 0.f, 0.f};

    const ushort_t* Bb = Bt + (size_t)col0 * K;
    int arow = wr * 64 + (l & 15);
    int brow = wc * 64 + (l & 15);
    int kb   = (l >> 4) * 8;

    #pragma unroll
    for (int k0 = 0; k0 < K; k0 += 32) {
        // A-stage: [128][32] = sum of 8 fp32 planes, converted to bf16.
        #pragma unroll
        for (int i = 0; i < 16; ++i) {
            int e2 = tid + 256 * i;
            int rr = e2 >> 5, cc = e2 & 31;
            size_t r = (size_t)(row0 + rr);
            float s = 0.f;
            #pragma unroll
            for (int z = 0; z < KSPLIT_XDBL; ++z)
                s += parts[(size_t)z * NROWS * XDBL_W + r * XDBL_W + k0 + cc];
            As[rr * 32 + cc] = f2bf(s);
        }
        stage128x32(Bb + k0, K, Bs, tid);
        __syncthreads();
        bf16x8 af[4], bfr[4];
        #pragma unroll
        for (int m = 0; m < 4; ++m)
            af[m] = *reinterpret_cast<const bf16x8*>(&As[(arow + m * 16) * 32 + kb]);
        #pragma unroll
        for (int n = 0; n < 4; ++n)
            bfr[n] = *reinterpret_cast<const bf16x8*>(&Bs[(brow + n * 16) * 32 + kb]);
        #pragma unroll
        for (int m = 0; m < 4; ++m)
            #pragma unroll
            for (int n = 0; n < 4; ++n)
                acc[m][n] = __builtin_amdgcn_mfma_f32_16x16x32_bf16(
                    af[m], bfr[n], acc[m][n], 0, 0, 0);
        __syncthreads();
    }

    int ro = (l >> 4) * 4, co = l & 15;
    #pragma unroll
    for (int m = 0; m < 4; ++m) {
        #pragma unroll
        for (int n = 0; n < 4; ++n) {
            int c = col0 + wc * 64 + n * 16 + co;
            float bdt = bias[c];
            #pragma unroll
            for (int reg = 0; reg < 4; ++reg) {
                int r = row0 + wr * 64 + m * 16 + ro + reg;
                float v = acc[m][n][reg] + bdt;
                v = (v > 20.f) ? v : __logf(1.f + __expf(v));   // softplus
                dtb[(size_t)r * D_INNER + c] = f2bf(v);
            }
        }
    }
}

// ---------------------------------------------------------------------------
// xdbl split-K GEMM, 64x128 tile, BK=32 (proven fast):
// parts[z][64-row-block][96] = u2 x WtXp^T over K-range.
// ---------------------------------------------------------------------------
__global__ __launch_bounds__(256)
void gemm_xdbl64(const ushort_t* __restrict__ A, const ushort_t* __restrict__ Bt,
                 float* __restrict__ parts)
{
    __shared__ ushort_t As[64 * 32];
    __shared__ ushort_t Bs[128 * 32];
    const int K = D_INNER;
    const int KS = D_INNER / KSPLIT_XDBL;      // 256
    int tid = threadIdx.x;
    int l = tid & 63, wid = tid >> 6;
    int wr = wid >> 1, wc = wid & 1;
    int row0 = blockIdx.y * 64;
    int kbeg = blockIdx.z * KS;

    f32x4 acc[2][4];
    #pragma unroll
    for (int m = 0; m < 2; ++m)
        #pragma unroll
        for (int n = 0; n < 4; ++n)
            acc[m][n] = (f32x4){0.f, 0.f, 0.f, 0.f};

    const ushort_t* Ab = A  + (size_t)row0 * K + kbeg;
    const ushort_t* Bb = Bt + kbeg;
    int arow = wr * 32 + (l & 15);
    int brow = wc * 64 + (l & 15);
    int kb   = (l >> 4) * 8;

    #pragma unroll
    for (int k0 = 0; k0 < KS; k0 += 32) {
        stage64x32(Ab + k0, K, As, tid);
        stage128x32(Bb + k0, K, Bs, tid);
        __syncthreads();
        bf16x8 af[2], bfr[4];
        #pragma unroll
        for (int m = 0; m < 2; ++m)
            af[m] = *reinterpret_cast<const bf16x8*>(&As[(arow + m * 16) * 32 + kb]);
        #pragma unroll
        for (int n = 0; n < 4; ++n)
            bfr[n] = *reinterpret_cast<const bf16x8*>(&Bs[(brow + n * 16) * 32 + kb]);
        #pragma unroll
        for (int m = 0; m < 2; ++m)
            #pragma unroll
            for (int n = 0; n < 4; ++n)
                acc[m][n] = __builtin_amdgcn_mfma_f32_16x16x32_bf16(
                    af[m], bfr[n], acc[m][n], 0, 0, 0);
        __syncthreads();
    }

    float* Cp = parts + (size_t)blockIdx.z * NROWS * XDBL_W;
    int ro = (l >> 4) * 4, co = l & 15;
    #pragma unroll
    for (int m = 0; m < 2; ++m) {
        #pragma unroll
        for (int n = 0; n < 4; ++n) {
            int c = wc * 64 + n * 16 + co;
            if (c >= XDBL_W) continue;
            #pragma unroll
            for (int reg = 0; reg < 4; ++reg) {
                int r = row0 + wr * 32 + m * 16 + ro + reg;
                Cp[(size_t)r * XDBL_W + c] = acc[m][n][reg];
            }
        }
    }
}

// ---------------------------------------------------------------------------
// out GEMM, 64x64 tile, BK=64, swizzled LDS: out = x + rs * (ybf x WtOut^T).
// ---------------------------------------------------------------------------
__global__ __launch_bounds__(256)
void gemm_out64(const ushort_t* __restrict__ A, const ushort_t* __restrict__ Bt,
                const float* __restrict__ x, const float* __restrict__ res_scale,
                float* __restrict__ out)
{
    __shared__ ushort_t As[64 * 64];
    __shared__ ushort_t Bs[64 * 64];
    const int K = D_INNER, N = D_MODEL;
    int bid = blockIdx.x;                       // 512
    int swzb = ((bid & 7) << 6) + (bid >> 3);
    int bx = swzb & 15, by = swzb >> 4;
    int tid = threadIdx.x;
    int l = tid & 63, wid = tid >> 6;
    int wr = wid >> 1, wc = wid & 1;
    int row0 = by * 64, col0 = bx * 64;

    f32x4 acc[2][2];
    #pragma unroll
    for (int m = 0; m < 2; ++m)
        #pragma unroll
        for (int n = 0; n < 2; ++n)
            acc[m][n] = (f32x4){0.f, 0.f, 0.f, 0.f};

    const ushort_t* Ab = A  + (size_t)row0 * K;
    const ushort_t* Bb = Bt + (size_t)col0 * K;
    int arow = wr * 32 + (l & 15);
    int brow = wc * 32 + (l & 15);

    for (int k0 = 0; k0 < K; k0 += 64) {
        stage64x64_swz(Ab + k0, K, As, tid);
        stage64x64_swz(Bb + k0, K, Bs, tid);
        __syncthreads();
        #pragma unroll
        for (int ks = 0; ks < 2; ++ks) {
            int sw = (((ks * 4 + (l >> 4)) ^ (l & 7)) * 8);
            bf16x8 af[2], bfr[2];
            #pragma unroll
            for (int m = 0; m < 2; ++m)
                af[m] = *reinterpret_cast<const bf16x8*>(
                    &As[(arow + m * 16) * 64 + sw]);
            #pragma unroll
            for (int n = 0; n < 2; ++n)
                bfr[n] = *reinterpret_cast<const bf16x8*>(
                    &Bs[(brow + n * 16) * 64 + sw]);
            #pragma unroll
            for (int m = 0; m < 2; ++m)
                #pragma unroll
                for (int n = 0; n < 2; ++n)
                    acc[m][n] = __builtin_amdgcn_mfma_f32_16x16x32_bf16(
                        af[m], bfr[n], acc[m][n], 0, 0, 0);
        }
        __syncthreads();
    }

    float rs = res_scale[0];
    int ro = (l >> 4) * 4, co = l & 15;
    #pragma unroll
    for (int m = 0; m < 2; ++m) {
        #pragma unroll
        for (int n = 0; n < 2; ++n) {
            int c = col0 + wc * 32 + n * 16 + co;
            #pragma unroll
            for (int reg = 0; reg < 4; ++reg) {
                int r = row0 + wr * 32 + m * 16 + ro + reg;
                out[(size_t)r * N + c] = x[(size_t)r * N + c] + rs * acc[m][n][reg];
            }
        }
    }
}

// ---------------------------------------------------------------------------
// Chunked scan, pass A: one thread per (channel, chunk); 16 states in regs.
// B row from bf16 xdblBC; hend written as bf16.
// ---------------------------------------------------------------------------
__global__ __launch_bounds__(256)
void scan_partial_kernel(const ushort_t* __restrict__ dtb,
                         const ushort_t* __restrict__ xdblBC,
                         const ushort_t* __restrict__ u2bf,
                         const float* __restrict__ A_log,
                         ushort_t* __restrict__ hend, float* __restrict__ sumdt_buf)
{
    int idx = blockIdx.x * 256 + threadIdx.x;   // 0 .. NCHAN*NCHUNK-1
    int p = idx & (NCHAN - 1);                  // channel (64 consecutive/wave)
    int c = idx >> 12;                          // chunk
    int b = p >> 11, e = p & (D_INNER - 1);

    float An[D_STATE];
    {
        const float4* ar = reinterpret_cast<const float4*>(A_log + (size_t)e * D_STATE);
        #pragma unroll
        for (int q = 0; q < 4; ++q) {
            float4 a4 = ar[q];
            An[q * 4 + 0] = -__expf(a4.x);
            An[q * 4 + 1] = -__expf(a4.y);
            An[q * 4 + 2] = -__expf(a4.z);
            An[q * 4 + 3] = -__expf(a4.w);
        }
    }
    float h[D_STATE];
    #pragma unroll
    for (int n = 0; n < D_STATE; ++n) h[n] = 0.f;
    float sdt = 0.f;

    size_t rowbase = (size_t)b * SEQLEN + c * LCHUNK;
    #pragma unroll
    for (int j = 0; j < LCHUNK; ++j) {
        size_t row = rowbase + j;
        float dt = bf2f(dtb[row * D_INNER + e]);
        float u  = bf2f(u2bf[row * D_INNER + e]);
        float dtu = dt * u;
        sdt += dt;
        const ushort8v* xr = reinterpret_cast<const ushort8v*>(xdblBC + row * 32);
        ushort8v b0 = xr[0], b1 = xr[1];
        float Bv[D_STATE];
        #pragma unroll
        for (int q = 0; q < 8; ++q) { Bv[q] = bf2f(b0[q]); Bv[8 + q] = bf2f(b1[q]); }
        #pragma unroll
        for (int n = 0; n < D_STATE; ++n)
            h[n] = __expf(dt * An[n]) * h[n] + dtu * Bv[n];
    }

    ushort8v o0, o1;
    #pragma unroll
    for (int q = 0; q < 8; ++q) { o0[q] = f2bf(h[q]); o1[q] = f2bf(h[8 + q]); }
    ushort8v* hp = reinterpret_cast<ushort8v*>(hend + ((size_t)p * NCHUNK + c) * D_STATE);
    hp[0] = o0; hp[1] = o1;
    sumdt_buf[p * NCHUNK + c] = sdt;
}

// ---------------------------------------------------------------------------
// Pass B: wave-shuffle inter-chunk scan — one WAVE per channel (lane = chunk,
// 16 states in registers). No barriers, no LDS. Same fp32 Hillis-Steele
// recurrence and combine order as the LDS version -> bit-identical carries.
// Block = 256 threads = 4 channels; grid = NCHAN/4.
// ---------------------------------------------------------------------------
__global__ __launch_bounds__(256)
void scan_combine_kernel(const float* __restrict__ A_log,
                         const float* __restrict__ sumdt_buf,
                         ushort_t* __restrict__ hend /* in: hend, out: hcarry */)
{
    int tid = threadIdx.x;
    int lane = tid & 63;                // chunk index
    int wv = tid >> 6;                  // channel slot within block
    int p = blockIdx.x * 4 + wv;
    int e = p & (D_INNER - 1);

    float An[D_STATE];
    {
        const float4* ar = reinterpret_cast<const float4*>(A_log + (size_t)e * D_STATE);
        #pragma unroll
        for (int q = 0; q < 4; ++q) {
            float4 a4 = ar[q];
            An[q * 4 + 0] = -__expf(a4.x);
            An[q * 4 + 1] = -__expf(a4.y);
            An[q * 4 + 2] = -__expf(a4.z);
            An[q * 4 + 3] = -__expf(a4.w);
        }
    }

    float sdt = sumdt_buf[p * NCHUNK + lane];
    float P[D_STATE], H[D_STATE];
    {
        const ushort8v* hp = reinterpret_cast<const ushort8v*>(
            hend + ((size_t)p * NCHUNK + lane) * D_STATE);
        ushort8v h0 = hp[0], h1 = hp[1];
        #pragma unroll
        for (int q = 0; q < 8; ++q) { H[q] = bf2f(h0[q]); H[8 + q] = bf2f(h1[q]); }
    }
    #pragma unroll
    for (int n = 0; n < D_STATE; ++n) P[n] = __expf(An[n] * sdt);

    // Inclusive Hillis-Steele scan over the 64-lane chunk axis.
    #pragma unroll
    for (int d = 1; d < 64; d <<= 1) {
        #pragma unroll
        for (int n = 0; n < D_STATE; ++n) {
            float Hl = __shfl_up(H[n], d);
            float Pl = __shfl_up(P[n], d);
            if (lane >= d) {
                H[n] = P[n] * Hl + H[n];   // (P,H) o (Pl,Hl)
                P[n] = P[n] * Pl;
            }
        }
    }

    // Exclusive carry = previous lane's inclusive H (0 for lane 0).
    ushort8v o0, o1;
    #pragma unroll
    for (int n = 0; n < D_STATE; ++n) {
        float cy = __shfl_up(H[n], 1);
        if (lane == 0) cy = 0.f;
        if (n < 8) o0[n] = f2bf(cy); else o1[n - 8] = f2bf(cy);
    }
    ushort8v* op = reinterpret_cast<ushort8v*>(
        hend + ((size_t)p * NCHUNK + lane) * D_STATE);
    op[0] = o0; op[1] = o1;
}

// ---------------------------------------------------------------------------
// Pass C: one thread per (channel, chunk), seeded with bf16 carry; in-register
// dot with C row; fused D-skip + SiLU(z) gate; writes y as bf16.
// ---------------------------------------------------------------------------
__global__ __launch_bounds__(256)
void scan_final_kernel(const ushort_t* __restrict__ dtb,
                       const ushort_t* __restrict__ xdblBC,
                       const ushort_t* __restrict__ xzbf, const ushort_t* __restrict__ u2bf,
                       ushort_t* __restrict__ ybf,
                       const float* __restrict__ A_log,
                       const float* __restrict__ D_param,
                       const ushort_t* __restrict__ hcarry)
{
    int idx = blockIdx.x * 256 + threadIdx.x;
    int p = idx & (NCHAN - 1);
    int c = idx >> 12;
    int b = p >> 11, e = p & (D_INNER - 1);
    float De = D_param[e];

    float An[D_STATE];
    {
        const float4* ar = reinterpret_cast<const float4*>(A_log + (size_t)e * D_STATE);
        #pragma unroll
        for (int q = 0; q < 4; ++q) {
            float4 a4 = ar[q];
            An[q * 4 + 0] = -__expf(a4.x);
            An[q * 4 + 1] = -__expf(a4.y);
            An[q * 4 + 2] = -__expf(a4.z);
            An[q * 4 + 3] = -__expf(a4.w);
        }
    }
    float h[D_STATE];
    {
        const ushort8v* hp = reinterpret_cast<const ushort8v*>(
            hcarry + ((size_t)p * NCHUNK + c) * D_STATE);
        ushort8v h0 = hp[0], h1 = hp[1];
        #pragma unroll
        for (int q = 0; q < 8; ++q) { h[q] = bf2f(h0[q]); h[8 + q] = bf2f(h1[q]); }
    }

    size_t rowbase = (size_t)b * SEQLEN + c * LCHUNK;
    #pragma unroll
    for (int j = 0; j < LCHUNK; ++j) {
        size_t row = rowbase + j;
        float dt = bf2f(dtb[row * D_INNER + e]);
        float u  = bf2f(u2bf[row * D_INNER + e]);
        float dtu = dt * u;
        const ushort8v* xr = reinterpret_cast<const ushort8v*>(xdblBC + row * 32);
        ushort8v b0 = xr[0], b1 = xr[1], c0v = xr[2], c1v = xr[3];
        float Bv[D_STATE], Cv[D_STATE];
        #pragma unroll
        for (int q = 0; q < 8; ++q) {
            Bv[q] = bf2f(b0[q]); Bv[8 + q] = bf2f(b1[q]);
            Cv[q] = bf2f(c0v[q]); Cv[8 + q] = bf2f(c1v[q]);
        }
        float y = 0.f;
        #pragma unroll
        for (int n = 0; n < D_STATE; ++n) {
            h[n] = __expf(dt * An[n]) * h[n] + dtu * Bv[n];
            y += h[n] * Cv[n];
        }
        float z  = bf2f(xzbf[row * (2 * D_INNER) + D_INNER + e]);
        float sz = z * fast_sigmoid(z);
        ybf[row * D_INNER + e] = f2bf((y + u * De) * sz);
    }
}

// ---------------------------------------------------------------------------
extern "C" void kernel_launch(void* const* d_in, const int* in_sizes, int n_in,
                              void* d_out, int out_size, void* d_ws, size_t ws_size,
                              hipStream_t stream)
{
    const float* x       = (const float*)d_in[0];
    const float* ln_g    = (const float*)d_in[1];
    const float* ln_b    = (const float*)d_in[2];
    const float* W_in    = (const float*)d_in[3];
    const float* conv_w  = (const float*)d_in[4];
    const float* conv_b  = (const float*)d_in[5];
    const float* W_xp    = (const float*)d_in[6];
    const float* W_dt    = (const float*)d_in[7];
    const float* b_dt    = (const float*)d_in[8];
    const float* A_log   = (const float*)d_in[9];
    const float* D_param = (const float*)d_in[10];
    const float* W_out   = (const float*)d_in[11];
    const float* res_sc  = (const float*)d_in[12];
    float* out = (float*)d_out;

    char* ws = (char*)d_ws;
    const size_t MB = 1024 * 1024;
    // Workspace (peak 82 MB):
    //   xzbf    [0,16M)      2048x4096 bf16 (only z cols 2048-4095 written)
    //   u2bf    [16M,24M)    2048x2048 bf16 (written by fused xz+conv)
    //   dtb16   [24M,32M)    2048x2048 bf16 (softplus'd dt)
    //   xdblBC  [32M,32.125M) 2048x32 bf16 (B cols 64..80, C cols 80..96)
    //   hend    [34M,42M)    4096x64x16 bf16 (carry in place)
    //   sumdt   [50M,51M)    4096x64 fp32
    //   xnbf    [51M,55M)    2048x1024 bf16
    //   WtIn    [55M,63M)    4096x1024 bf16
    //   WtOut   [63M,67M)    1024x2048 bf16
    //   WtXp    [67M,67.5M)  128x2048 bf16 (rows 96..127 zeroed via col guard)
    //   WtDt    [67.5M,68M)  2048x64 bf16
    //   ybf     [68M,76M)    2048x2048 bf16
    //   partsX  [76M,82M)    8x2048x96 fp32
    ushort_t* xzbf   = (ushort_t*)(ws);
    ushort_t* u2bf   = (ushort_t*)(ws + 16 * MB);
    ushort_t* dtb16  = (ushort_t*)(ws + 24 * MB);
    ushort_t* xdblBC = (ushort_t*)(ws + 32 * MB);
    ushort_t* hend   = (ushort_t*)(ws + 34 * MB);
    float*    sumdt  = (float*)(ws + 50 * MB);
    ushort_t* xnbf   = (ushort_t*)(ws + 51 * MB);
    ushort_t* WtIn   = (ushort_t*)(ws + 55 * MB);
    ushort_t* WtOut  = (ushort_t*)(ws + 63 * MB);
    ushort_t* WtXp   = (ushort_t*)(ws + 67 * MB);
    ushort_t* WtDt   = (ushort_t*)(ws + 67 * MB + 512 * 1024);
    ushort_t* ybf    = (ushort_t*)(ws + 68 * MB);
    float*    partsX = (float*)(ws + 76 * MB);

    // 0+1. mega-prologue: LayerNorm + all weight transposes (+WtXp pad)
    prologue_kernel<<<PRO_TOTAL, 256, 0, stream>>>(
        x, ln_g, ln_b, xnbf, W_in, WtIn, W_out, WtOut, W_xp, WtXp, W_dt, WtDt);

    // 2+3. xz = xn @ W_in fused with causal conv + SiLU (swizzled LDS)
    gemm_xz_conv<<<512, 256, 0, stream>>>(
        xnbf, WtIn, xzbf, conv_w, conv_b, u2bf);

    // 4. xdbl partials = u2 @ W_xp  [2048 x 96, K=2048]  64-row-tile split-K x8
    {
        dim3 grid(1, NROWS / 64, KSPLIT_XDBL);
        gemm_xdbl64<<<grid, 256, 0, stream>>>(u2bf, WtXp, partsX);
    }

    // 5. dt = softplus(sum(parts)[:, :64] @ W_dt + b_dt)  (fused reduce+GEMM);
    //    bx==0 blocks also emit xdblBC bf16 (B/C cols).
    {
        dim3 grid(D_INNER / 128, NROWS / 128);
        gemm_dt_fused<<<grid, 256, 0, stream>>>(partsX, WtDt, dtb16, b_dt, xdblBC);
    }

    // 6. chunked parallel scan (A: partials, B: wave-shuffle inter-chunk,
    //    C: final+gate)
    scan_partial_kernel<<<(NCHAN * NCHUNK) / 256, 256, 0, stream>>>(
        dtb16, xdblBC, u2bf, A_log, hend, sumdt);
    scan_combine_kernel<<<NCHAN / 4, 256, 0, stream>>>(A_log, sumdt, hend);
    scan_final_kernel<<<(NCHAN * NCHUNK) / 256, 256, 0, stream>>>(
        dtb16, xdblBC, xzbf, u2bf, ybf, A_log, D_param, hend);

    // 7. out = x + rs * (y @ W_out)  [2048 x 1024, K=2048]  64x64 BK=64 swz
    gemm_out64<<<512, 256, 0, stream>>>(ybf, WtOut, x, res_sc, out);
}